// Round 4
// baseline (4176.114 us; speedup 1.0000x reference)
//
#include <hip/hip_runtime.h>
#include <hip/hip_bf16.h>
#include <stdint.h>

#define NLAYER 8
#define HDIM   768
#define EDIM   1536
#define NST    16
#define LSEQ   2048
#define BATCH  2
#define BLTOK  (BATCH*LSEQ)   /* 4096 tokens */
#define NCH    (BATCH*EDIM)   /* 3072 scan channels */
#define NCHK   64             /* scan time chunks */

typedef unsigned short u16;
typedef short  short8  __attribute__((ext_vector_type(8)));
typedef float  f32x4   __attribute__((ext_vector_type(4)));
typedef unsigned short u16x4 __attribute__((ext_vector_type(4)));

__device__ __forceinline__ float sigm(float x){ return 1.0f/(1.0f+__expf(-x)); }

__device__ __forceinline__ u16 bf16_rne(float x){
  unsigned u = __float_as_uint(x);
  return (u16)((u + 0x7fffu + ((u>>16)&1u)) >> 16);
}
__device__ __forceinline__ float bf16_f(u16 h){
  return __uint_as_float(((unsigned)h)<<16);
}

// async 16B global -> LDS DMA
__device__ __forceinline__ void gload16(const void* g, void* l){
  __builtin_amdgcn_global_load_lds(
    reinterpret_cast<const __attribute__((address_space(1))) unsigned*>(
        reinterpret_cast<uintptr_t>(g)),
    reinterpret_cast<__attribute__((address_space(3))) unsigned*>(
        reinterpret_cast<uintptr_t>(l)),
    16, 0, 0);
}

// ---------------------------------------------------------------------------
// Weight prep: W[K][Nsrc] fp32 -> H/L[Ndst][K] bf16 hi/lo (transposed).
// ---------------------------------------------------------------------------
__global__ __launch_bounds__(256) void wprep_k(
    const float* __restrict__ W, u16* __restrict__ H, u16* __restrict__ L,
    int Nsrc, int Ndst, int K)
{
  __shared__ float T[32][33];
  int z = blockIdx.z;
  W += (size_t)z*K*Nsrc; H += (size_t)z*Ndst*K; L += (size_t)z*Ndst*K;
  int n0 = blockIdx.x*32, k0 = blockIdx.y*32;
  int tx = threadIdx.x&31, ty = threadIdx.x>>5;
  #pragma unroll
  for (int r=0;r<4;r++){
    int kk = ty+8*r, col = n0+tx;
    T[kk][tx] = (col<Nsrc) ? W[(size_t)(k0+kk)*Nsrc+col] : 0.f;
  }
  __syncthreads();
  #pragma unroll
  for (int r=0;r<4;r++){
    int nn = ty+8*r, n = n0+nn, k = k0+tx;
    if (n<Ndst){
      float f = T[tx][nn];
      u16 h = bf16_rne(f);
      H[(size_t)n*K+k] = h;
      L[(size_t)n*K+k] = bf16_rne(f - bf16_f(h));
    }
  }
}

// ---------------------------------------------------------------------------
// Unified MFMA GEMM, DMA-staged, LDS double-buffered + REGISTER frag
// prefetch: one barrier per k-step; ds_reads of step t+1 overlap MFMA of
// step t; STAGE(t+2) DMA overlaps both.
// A: bf16 hi plane AH (+ lo plane AL for SPLIT==3), row-major [M][lda].
// W: pre-split planes WH/WL, row-major [N][ldw].
// Tile 128x128, BK=32, 4 waves, 4x4 of 16x16x32 MFMA.
// SPLIT: 3 = bf16x3 (fp32-like), 1 = plain bf16.
// EPI bits: 1=SiLU, 2=C+=v, 8=store bf16 u16, 16=atomicAdd f32.
// ---------------------------------------------------------------------------
template<int EPI, int SPLIT, int SPLITK>
__global__ __launch_bounds__(256) void gemm_u(
    const u16* __restrict__ AH, const u16* __restrict__ AL, int lda,
    const u16* __restrict__ WH, const u16* __restrict__ WL, int ldw,
    const float* __restrict__ bias, void* __restrict__ Cout,
    int N, int Kloop, size_t zA, size_t zW, size_t zB, size_t zC)
{
  constexpr int NPL = (SPLIT==3)?4:2;        // planes per buffer
  constexpr int NLD = (SPLIT==3)?8:4;        // DMA issues/thread/k-step
  __shared__ __align__(16) u16 smem[2*NPL*4096];

  const int z = blockIdx.z;
  const u16* ah = AH + (size_t)z*zA;
  const u16* bh = WH + (size_t)z*zW;
  const u16* al = nullptr;
  const u16* bl = nullptr;
  if constexpr (SPLIT==3){ al = AL + (size_t)z*zA; bl = WL + (size_t)z*zW; }

  const int tid  = threadIdx.x;
  const int m0 = blockIdx.y<<7, n0 = blockIdx.x<<7;
  const int wave = tid>>6, lane = tid&63;
  const int r = lane&15, q = lane>>4;
  const int wm = (wave&1)<<6, wn = (wave>>1)<<6;
  const int srow = tid>>2;        // 0..63 (row within 64-row half)
  const int scol = (tid&3)*8;     // u16 col offset (0,8,16,24)
  const int sdst = tid*8;         // u16 LDS offset of this thread's 16B

  const int nk = Kloop >> 5;

  auto STAGE = [&](int idx){
    u16* s = smem + (size_t)(idx&1)*NPL*4096;
    const int k0 = idx<<5;
    #pragma unroll
    for (int i=0;i<2;i++){
      const size_t gao = (size_t)(m0 + i*64 + srow)*lda + k0 + scol;
      const size_t gbo = (size_t)(n0 + i*64 + srow)*ldw + k0 + scol;
      const int lo = i*2048 + sdst;
      gload16(ah+gao, s+lo);
      gload16(bh+gbo, s+4096+lo);
      if constexpr (SPLIT==3){
        gload16(al+gao, s+2*4096+lo);
        gload16(bl+gbo, s+3*4096+lo);
      }
    }
  };

  // two statically-named frag sets (rule #20: no runtime-indexed reg arrays)
  short8 aH0[4], bH0[4], aL0[4], bL0[4];
  short8 aH1[4], bH1[4], aL1[4], bL1[4];

  auto LOADF = [&](short8* fa, short8* fb, short8* fc, short8* fd, int par){
    const u16* s = smem + (size_t)par*NPL*4096;
    #pragma unroll
    for (int i=0;i<4;i++) fa[i] = *(const short8*)&s[(wm + 16*i + r)*32 + q*8];
    #pragma unroll
    for (int j=0;j<4;j++) fb[j] = *(const short8*)&s[4096 + (wn + 16*j + r)*32 + q*8];
    if constexpr (SPLIT==3){
      #pragma unroll
      for (int i=0;i<4;i++) fc[i] = *(const short8*)&s[2*4096 + (wm + 16*i + r)*32 + q*8];
      #pragma unroll
      for (int j=0;j<4;j++) fd[j] = *(const short8*)&s[3*4096 + (wn + 16*j + r)*32 + q*8];
    }
  };

  f32x4 acc[4][4];
  #pragma unroll
  for (int i=0;i<4;i++)
    #pragma unroll
    for (int j=0;j<4;j++)
      #pragma unroll
      for (int t=0;t<4;t++) acc[i][j][t]=0.f;

  auto MM = [&](short8* fa, short8* fb, short8* fc, short8* fd){
    if constexpr (SPLIT==3){
      #pragma unroll
      for (int i=0;i<4;i++)
        #pragma unroll
        for (int j=0;j<4;j++){
          acc[i][j] = __builtin_amdgcn_mfma_f32_16x16x32_bf16(fa[i], fb[j], acc[i][j], 0,0,0);
          acc[i][j] = __builtin_amdgcn_mfma_f32_16x16x32_bf16(fa[i], fd[j], acc[i][j], 0,0,0);
          acc[i][j] = __builtin_amdgcn_mfma_f32_16x16x32_bf16(fc[i], fb[j], acc[i][j], 0,0,0);
        }
    } else {
      #pragma unroll
      for (int i=0;i<4;i++)
        #pragma unroll
        for (int j=0;j<4;j++)
          acc[i][j] = __builtin_amdgcn_mfma_f32_16x16x32_bf16(fa[i], fb[j], acc[i][j], 0,0,0);
    }
  };

  // ---- prologue
  STAGE(0);
  if (nk > 1){
    STAGE(1);
    asm volatile("s_waitcnt vmcnt(%0)" :: "n"(NLD) : "memory");  // buf0 landed
  } else {
    asm volatile("s_waitcnt vmcnt(0)" ::: "memory");
  }
  __builtin_amdgcn_s_barrier();
  LOADF(aH0,bH0,aL0,bL0, 0);

  // per step t (prefetching t+1):
  //   lgkm(0): all my reads of buf(t) done   -> barrier makes it block-wide
  //   vmcnt(0): buf(t+1) DMA landed          -> barrier makes it block-wide
  //   STAGE(t+2) overwrites buf(t) (safe after barrier)
  //   LOADF(t+1) overlaps MM(t)
  #define GBODY(T, A,B,C,D, A2,B2,C2,D2)                              \
    if ((T)+1 < nk){                                                  \
      asm volatile("s_waitcnt lgkmcnt(0)" ::: "memory");              \
      asm volatile("s_waitcnt vmcnt(0)" ::: "memory");                \
      __builtin_amdgcn_s_barrier();                                   \
      if ((T)+2 < nk) STAGE((T)+2);                                   \
      LOADF(A2,B2,C2,D2, ((T)+1)&1);                                  \
    }                                                                 \
    MM(A,B,C,D);

  int t = 0;
  for (; t+1 < nk; t += 2){
    GBODY(t,   aH0,bH0,aL0,bL0, aH1,bH1,aL1,bL1);
    GBODY(t+1, aH1,bH1,aL1,bL1, aH0,bH0,aL0,bL0);
  }
  if (t < nk){ MM(aH0,bH0,aL0,bL0); }
  #undef GBODY

  float* Cf = (float*)Cout + (size_t)z*zC;
  u16*   Cu = (u16*)Cout   + (size_t)z*zC;
  const float* bz = bias ? (bias + (size_t)z*zB) : bias;
  #pragma unroll
  for (int j=0;j<4;j++){
    int n_out = n0 + wn + 16*j + r;
    float bv = (bz && (!SPLITK || z==0)) ? bz[n_out] : 0.f;
    #pragma unroll
    for (int i=0;i<4;i++){
      #pragma unroll
      for (int reg=0;reg<4;reg++){
        int m_out = m0 + wm + 16*i + 4*q + reg;
        float v = acc[i][j][reg] + bv;
        if (EPI & 1) v *= sigm(v);
        size_t o = (size_t)m_out*N + n_out;
        if      (EPI & 16) atomicAdd(&Cf[o], v);
        else if (EPI & 8)  Cu[o] = bf16_rne(v);
        else if (EPI & 2)  Cf[o] += v;
        else               Cf[o] = v;
      }
    }
  }
}

// ---------------------------------------------------------------------------
// xproj GEMM: DBC[4096][36] = U[4096][1536] @ xw; pre-split xwT[48][1536].
// ---------------------------------------------------------------------------
__global__ __launch_bounds__(64) void xgemm_k(
    const float* __restrict__ A, const u16* __restrict__ XH,
    const u16* __restrict__ XL, float* __restrict__ DBC)
{
  int m0 = blockIdx.x*16;
  int lane = threadIdx.x;
  int r = lane&15, q = lane>>4;
  f32x4 acc[3];
  #pragma unroll
  for (int j=0;j<3;j++)
    #pragma unroll
    for (int t=0;t<4;t++) acc[j][t]=0.f;

  for (int k0 = 0; k0 < EDIM; k0 += 32){
    const float* ap = A + (size_t)(m0+r)*EDIM + k0 + q*8;
    float f[8];
    *(float4*)&f[0] = *(const float4*)(ap+0);
    *(float4*)&f[4] = *(const float4*)(ap+4);
    short8 ah, al;
    #pragma unroll
    for (int t=0;t<8;t++){
      u16 h = bf16_rne(f[t]);
      ah[t] = (short)h;
      al[t] = (short)bf16_rne(f[t]-bf16_f(h));
    }
    #pragma unroll
    for (int j=0;j<3;j++){
      size_t o = (size_t)(16*j+r)*EDIM + k0 + q*8;
      short8 bh = *(const short8*)&XH[o];
      short8 bl = *(const short8*)&XL[o];
      acc[j] = __builtin_amdgcn_mfma_f32_16x16x32_bf16(ah, bh, acc[j], 0,0,0);
      acc[j] = __builtin_amdgcn_mfma_f32_16x16x32_bf16(ah, bl, acc[j], 0,0,0);
      acc[j] = __builtin_amdgcn_mfma_f32_16x16x32_bf16(al, bh, acc[j], 0,0,0);
    }
  }
  #pragma unroll
  for (int j=0;j<3;j++){
    int n = 16*j + r;
    if (n < 36){
      #pragma unroll
      for (int reg=0;reg<4;reg++){
        int m = m0 + 4*q + reg;
        DBC[(size_t)m*36 + n] = acc[j][reg];
      }
    }
  }
}

// ---------------------------------------------------------------------------
__global__ __launch_bounds__(256) void embed_k(
    const int* __restrict__ ids, const float* __restrict__ tok,
    const float* __restrict__ pos, float* __restrict__ HS)
{
  int idx = blockIdx.x*256 + threadIdx.x;
  int h = idx % HDIM; int t = idx / HDIM;
  int lpos = t % LSEQ;
  int id = ids[t];
  HS[idx] = tok[id*HDIM + h] + pos[lpos*HDIM + h];
}

// ---------------------------------------------------------------------------
// PACK=1: write bf16 hi/lo planes (O1=H, O2=L). PACK=0: fp32 to O1.
template<int PACK>
__global__ __launch_bounds__(256) void ln_k(
    const float* __restrict__ X, const float* __restrict__ w,
    const float* __restrict__ b, void* __restrict__ O1, void* __restrict__ O2)
{
  int t = blockIdx.x;
  const float* x = X + (size_t)t*HDIM;
  float s=0.f, s2=0.f;
  for (int i=threadIdx.x; i<HDIM; i+=256){ float v=x[i]; s+=v; s2+=v*v; }
  #pragma unroll
  for (int off=32; off; off>>=1){ s += __shfl_down(s,off,64); s2 += __shfl_down(s2,off,64); }
  __shared__ float rs[4], rs2[4], mv[2];
  int lane = threadIdx.x & 63, wv = threadIdx.x >> 6;
  if (!lane){ rs[wv]=s; rs2[wv]=s2; }
  __syncthreads();
  if (!threadIdx.x){
    float a = rs[0]+rs[1]+rs[2]+rs[3];
    float c = rs2[0]+rs2[1]+rs2[2]+rs2[3];
    float m = a/HDIM;
    mv[0]=m; mv[1]=rsqrtf(c/HDIM - m*m + 1e-5f);
  }
  __syncthreads();
  float m = mv[0], r = mv[1];
  for (int i=threadIdx.x; i<HDIM; i+=256){
    float v = (x[i]-m)*r*w[i] + b[i];
    if (PACK){
      u16 h = bf16_rne(v);
      ((u16*)O1)[(size_t)t*HDIM+i] = h;
      ((u16*)O2)[(size_t)t*HDIM+i] = bf16_rne(v - bf16_f(h));
    } else {
      ((float*)O1)[(size_t)t*HDIM+i] = v;
    }
  }
}

// fp32 -> bf16 (hi only) convert, 4 elems/thread
__global__ __launch_bounds__(256) void cvt_k(
    const float* __restrict__ X, u16* __restrict__ O)
{
  int i = blockIdx.x*256 + threadIdx.x;
  float4 v = ((const float4*)X)[i];
  u16x4 o;
  o[0]=bf16_rne(v.x); o[1]=bf16_rne(v.y); o[2]=bf16_rne(v.z); o[3]=bf16_rne(v.w);
  ((u16x4*)O)[i] = o;
}

// ---------------------------------------------------------------------------
__global__ __launch_bounds__(256) void conv_silu_k(
    const float* __restrict__ PROJ, const float* __restrict__ cw,
    const float* __restrict__ cb, float* __restrict__ U)
{
  int idx = blockIdx.x*256 + threadIdx.x;
  int e = idx % EDIM; int t = idx / EDIM;
  int l = t % LSEQ; int tb = t - l;
  float acc = cb[e];
  #pragma unroll
  for (int j=0;j<4;j++){
    int tt = l + j - 3;
    if (tt >= 0) acc += PROJ[(size_t)(tb+tt)*(2*EDIM) + e] * cw[e*4+j];
  }
  U[idx] = acc * sigm(acc);
}

// ---------------------------------------------------------------------------
// Coalesced chunked scan: thread = (channel, chunk), 16 states in registers.
// ---------------------------------------------------------------------------
__global__ __launch_bounds__(256) void scanA_k(
    const float* __restrict__ U, const float* __restrict__ DBC,
    const float* __restrict__ Alog, const float* __restrict__ dtw,
    const float* __restrict__ dtb, float* __restrict__ PSP,
    float* __restrict__ PSS)
{
  const int CH = LSEQ/NCHK;
  int el = threadIdx.x & 63, jj = threadIdx.x >> 6;
  int ch = blockIdx.x*64 + el;
  int j  = blockIdx.y*4 + jj;
  int e = ch % EDIM, b = ch / EDIM;

  float a[16], P[16], S[16];
  #pragma unroll
  for (int n=0;n<16;n++){ a[n] = -__expf(Alog[e*NST+n]); P[n]=1.f; S[n]=0.f; }
  float w0=dtw[e], w1=dtw[EDIM+e], w2=dtw[2*EDIM+e], w3=dtw[3*EDIM+e];
  float db=dtb[e];
  size_t base=(size_t)b*LSEQ;

  for (int t=j*CH; t<j*CH+CH; t++){
    size_t tok = base+t;
    float4 d4 = *(const float4*)&DBC[tok*36];
    float4 B0 = *(const float4*)&DBC[tok*36+4];
    float4 B1 = *(const float4*)&DBC[tok*36+8];
    float4 B2 = *(const float4*)&DBC[tok*36+12];
    float4 B3 = *(const float4*)&DBC[tok*36+16];
    float dt = d4.x*w0 + d4.y*w1 + d4.z*w2 + d4.w*w3 + db;
    dt = (dt>20.f)?dt:log1pf(__expf(dt));
    float du = dt * U[tok*EDIM+e];
    float Bv[16];
    *(float4*)&Bv[0]=B0; *(float4*)&Bv[4]=B1; *(float4*)&Bv[8]=B2; *(float4*)&Bv[12]=B3;
    #pragma unroll
    for (int n=0;n<16;n++){
      float dA = __expf(dt*a[n]);
      P[n]*=dA; S[n]=S[n]*dA + du*Bv[n];
    }
  }
  #pragma unroll
  for (int n=0;n<16;n++){
    PSP[(size_t)(j*16+n)*NCH + ch] = P[n];
    PSS[(size_t)(j*16+n)*NCH + ch] = S[n];
  }
}

// Sequential combine over chunks; rewrites PSS in place with the INCOMING
// state of each chunk (consumed by scanC).
__global__ __launch_bounds__(256) void scanB_k(
    const float* __restrict__ PSP, float* __restrict__ PSS)
{
  int idx = blockIdx.x*256 + threadIdx.x;   // over NCH*16
  int n = idx / NCH, ch = idx % NCH;
  float hin = 0.f;
  #pragma unroll 4
  for (int jj=0;jj<NCHK;jj++){
    size_t o = (size_t)(jj*16+n)*NCH + ch;
    float p = PSP[o], s = PSS[o];
    PSS[o] = hin;
    hin = p*hin + s;
  }
}

__global__ __launch_bounds__(256) void scanC_k(
    const float* __restrict__ U, const float* __restrict__ DBC,
    const float* __restrict__ Alog, const float* __restrict__ dtw,
    const float* __restrict__ dtb, const float* __restrict__ HIN,
    const float* __restrict__ Dp, const float* __restrict__ PROJ,
    u16* __restrict__ YH, u16* __restrict__ YL)
{
  const int CH = LSEQ/NCHK;
  int el = threadIdx.x & 63, jj = threadIdx.x >> 6;
  int ch = blockIdx.x*64 + el;
  int j  = blockIdx.y*4 + jj;
  int e = ch % EDIM, b = ch / EDIM;

  float a[16], h[16];
  #pragma unroll
  for (int n=0;n<16;n++){
    a[n] = -__expf(Alog[e*NST+n]);
    h[n] = HIN[(size_t)(j*16+n)*NCH + ch];
  }
  float w0=dtw[e], w1=dtw[EDIM+e], w2=dtw[2*EDIM+e], w3=dtw[3*EDIM+e];
  float db=dtb[e], dcf=Dp[e];
  size_t base=(size_t)b*LSEQ;

  for (int t=j*CH; t<j*CH+CH; t++){
    size_t tok = base+t;
    float4 d4 = *(const float4*)&DBC[tok*36];
    float4 B0 = *(const float4*)&DBC[tok*36+4];
    float4 B1 = *(const float4*)&DBC[tok*36+8];
    float4 B2 = *(const float4*)&DBC[tok*36+12];
    float4 B3 = *(const float4*)&DBC[tok*36+16];
    float4 C0 = *(const float4*)&DBC[tok*36+20];
    float4 C1 = *(const float4*)&DBC[tok*36+24];
    float4 C2 = *(const float4*)&DBC[tok*36+28];
    float4 C3 = *(const float4*)&DBC[tok*36+32];
    float dt = d4.x*w0 + d4.y*w1 + d4.z*w2 + d4.w*w3 + db;
    dt = (dt>20.f)?dt:log1pf(__expf(dt));
    float u = U[tok*EDIM+e];
    float du = dt * u;
    float Bv[16], Cv[16];
    *(float4*)&Bv[0]=B0; *(float4*)&Bv[4]=B1; *(float4*)&Bv[8]=B2; *(float4*)&Bv[12]=B3;
    *(float4*)&Cv[0]=C0; *(float4*)&Cv[4]=C1; *(float4*)&Cv[8]=C2; *(float4*)&Cv[12]=C3;
    float y = 0.f;
    #pragma unroll
    for (int n=0;n<16;n++){
      float dA = __expf(dt*a[n]);
      h[n] = h[n]*dA + du*Bv[n];
      y += h[n]*Cv[n];
    }
    float g = PROJ[tok*(2*EDIM) + EDIM + e];
    float yv = (y + u*dcf)*sigm(g);
    u16 hh = bf16_rne(yv);
    YH[tok*EDIM + e] = hh;
    YL[tok*EDIM + e] = bf16_rne(yv - bf16_f(hh));
  }
}

// HS += (FB0 + FB1 + FB2)/6
__global__ __launch_bounds__(256) void addscale3_k(
    float* __restrict__ HS, const float* __restrict__ FB)
{
  const size_t S = (size_t)BLTOK*HDIM;
  size_t i = blockIdx.x*256 + threadIdx.x;
  HS[i] += (FB[i] + FB[i+S] + FB[i+2*S]) * (0.5f/3.0f);
}

// ---------------------------------------------------------------------------
extern "C" void kernel_launch(void* const* d_in, const int* in_sizes, int n_in,
                              void* d_out, int out_size, void* d_ws, size_t ws_size,
                              hipStream_t stream)
{
  const int*   ids      = (const int*)d_in[0];
  const float* tok_emb  = (const float*)d_in[1];
  const float* pos_emb  = (const float*)d_in[2];
  const float* ln_w     = (const float*)d_in[3];
  const float* ln_b     = (const float*)d_in[4];
  const float* in_w     = (const float*)d_in[5];
  const float* in_b     = (const float*)d_in[6];
  const float* conv_w   = (const float*)d_in[7];
  const float* conv_b   = (const float*)d_in[8];
  const float* xproj_w  = (const float*)d_in[9];
  const float* dt_w     = (const float*)d_in[10];
  const float* dt_b     = (const float*)d_in[11];
  const float* A_log    = (const float*)d_in[12];
  const float* Dp       = (const float*)d_in[13];
  const float* out_w    = (const float*)d_in[14];
  const float* out_b    = (const float*)d_in[15];
  const float* frac_w   = (const float*)d_in[16];
  const float* frac_b   = (const float*)d_in[17];
  const float* fln_w    = (const float*)d_in[18];
  const float* fln_b    = (const float*)d_in[19];

  // ---- workspace map
  const size_t F_HS   = (size_t)BLTOK*HDIM;      // 3,145,728 floats
  const size_t F_PROJ = (size_t)BLTOK*2*EDIM;    // 12,582,912
  const size_t F_R1   = (size_t)BLTOK*EDIM;      //  6,291,456
  float* HS   = (float*)d_ws;
  float* PROJ = HS   + F_HS;
  float* R1   = PROJ + F_PROJ;                   // XH/XL, then U
  float* DBC  = R1   + F_R1;
  u16* W16  = (u16*)(DBC + (size_t)BLTOK*36);
  u16* inH  = W16;
  u16* inL  = inH  + (size_t)2359296;
  u16* outH = inL  + (size_t)2359296;
  u16* outL = outH + (size_t)1179648;
  u16* frH  = outL + (size_t)1179648;
  u16* frL  = frH  + (size_t)1769472;
  u16* xH   = frL  + (size_t)1769472;
  u16* xL   = xH   + (size_t)73728;
  float* PSP = (float*)(xL + (size_t)73728);
  float* PSS = PSP + (size_t)NCHK*16*NCH;        // 12.6 MB each
  u16* YH  = (u16*)(PSS + (size_t)NCHK*16*NCH);  // 4096x1536 u16
  u16* YL  = YH + (size_t)BLTOK*EDIM;
  // aliases
  u16*   XH  = (u16*)R1;                         // LN hi plane (dead before U)
  u16*   XL  = XH + F_HS;                        // LN lo plane
  float* U   = R1;                               // fp32 conv out (overwrites X)
  u16*   HSB = (u16*)PSP;                        // bf16(HS), PSP dead post-scanB
  float* FB  = PROJ;                             // fractal stage3 out, 3*F_HS f32
  u16*   S1  = (u16*)(PROJ + 3*F_HS);            // stage1 out, 3*F_HS u16
  u16*   S2  = S1 + 3*F_HS;                      // stage2 out, 3*F_HS u16

  embed_k<<<(BLTOK*HDIM)/256, 256, 0, stream>>>(ids, tok_emb, pos_emb, HS);

  const size_t zWf = (size_t)HDIM*HDIM;
  for (int l = 0; l < NLAYER; l++){
    wprep_k<<<dim3(3072/32, 768/32), 256, 0, stream>>>(
        in_w + (size_t)l*HDIM*2*EDIM, inH, inL, 2*EDIM, 2*EDIM, HDIM);
    wprep_k<<<dim3(768/32, 1536/32), 256, 0, stream>>>(
        out_w + (size_t)l*EDIM*HDIM, outH, outL, HDIM, HDIM, EDIM);
    wprep_k<<<dim3(768/32, 768/32, 3), 256, 0, stream>>>(
        frac_w + (size_t)l*3*HDIM*HDIM, frH, frL, HDIM, HDIM, HDIM);
    wprep_k<<<dim3(2, 1536/32), 256, 0, stream>>>(
        xproj_w + (size_t)l*EDIM*36, xH, xL, 36, 48, EDIM);

    // LN -> bf16 hi/lo planes
    ln_k<1><<<BLTOK, 256, 0, stream>>>(HS, ln_w + l*HDIM, ln_b + l*HDIM, XH, XL);

    // proj = LN(hs) @ in_w + in_b   [4096 x 768 -> 3072], bf16x3
    gemm_u<0,3,0><<<dim3(24, 32), 256, 0, stream>>>(
        XH, XL, HDIM, inH, inL, HDIM, in_b + l*2*EDIM, PROJ,
        2*EDIM, HDIM, 0,0,0,0);

    conv_silu_k<<<(BLTOK*EDIM)/256, 256, 0, stream>>>(
        PROJ, conv_w + l*EDIM*4, conv_b + l*EDIM, U);

    // dbc = u @ xproj_w
    xgemm_k<<<BLTOK/16, 64, 0, stream>>>(U, xH, xL, DBC);

    // selective scan (coalesced 3-phase), Y -> bf16 hi/lo planes
    scanA_k<<<dim3(NCH/64, NCHK/4), 256, 0, stream>>>(
        U, DBC, A_log + (size_t)l*EDIM*NST, dt_w + (size_t)l*4*EDIM,
        dt_b + (size_t)l*EDIM, PSP, PSS);
    scanB_k<<<(NCH*16)/256, 256, 0, stream>>>(PSP, PSS);
    scanC_k<<<dim3(NCH/64, NCHK/4), 256, 0, stream>>>(
        U, DBC, A_log + (size_t)l*EDIM*NST, dt_w + (size_t)l*4*EDIM,
        dt_b + (size_t)l*EDIM, PSS, Dp + (size_t)l*EDIM, PROJ, YH, YL);

    // hs += y @ out_w + out_b  [4096 x 1536 -> 768], bf16x3, split-K=2, atomic
    gemm_u<16,3,1><<<dim3(6, 32, 2), 256, 0, stream>>>(
        YH, YL, EDIM, outH, outL, EDIM, out_b + l*HDIM, HS,
        HDIM, EDIM/2, /*zA*/EDIM/2, /*zW*/EDIM/2, 0, 0);

    // bf16 copy of HS for fractal stage1 A-operand
    cvt_k<<<(BLTOK*HDIM)/1024, 256, 0, stream>>>(HS, HSB);

    // fractal: plain bf16 (error attenuated /6), 3 z-batched stages
    gemm_u<9,1,0><<<dim3(6, 32, 3), 256, 0, stream>>>(
        HSB, nullptr, HDIM, frH, frL, HDIM, frac_b + (size_t)l*3*HDIM, S1,
        HDIM, HDIM, 0, zWf, HDIM, F_HS);
    gemm_u<9,1,0><<<dim3(6, 32, 3), 256, 0, stream>>>(
        S1, nullptr, HDIM, frH, frL, HDIM, frac_b + (size_t)l*3*HDIM, S2,
        HDIM, HDIM, F_HS, zWf, HDIM, F_HS);
    gemm_u<1,1,0><<<dim3(6, 32, 3), 256, 0, stream>>>(
        S2, nullptr, HDIM, frH, frL, HDIM, frac_b + (size_t)l*3*HDIM, FB,
        HDIM, HDIM, F_HS, zWf, HDIM, F_HS);

    addscale3_k<<<(BLTOK*HDIM)/256, 256, 0, stream>>>(HS, FB);
  }

  ln_k<0><<<BLTOK, 256, 0, stream>>>(HS, fln_w, fln_b, (float*)d_out, nullptr);
}

// Round 6
// 3882.793 us; speedup vs baseline: 1.0755x; 1.0755x over previous
//
#include <hip/hip_runtime.h>
#include <hip/hip_bf16.h>
#include <stdint.h>

#define NLAYER 8
#define HDIM   768
#define EDIM   1536
#define NST    16
#define LSEQ   2048
#define BATCH  2
#define BLTOK  (BATCH*LSEQ)   /* 4096 tokens */
#define NCH    (BATCH*EDIM)   /* 3072 scan channels */
#define NCHK   64             /* scan time chunks */

typedef unsigned short u16;
typedef short  short8  __attribute__((ext_vector_type(8)));
typedef float  f32x4   __attribute__((ext_vector_type(4)));
typedef unsigned short u16x4 __attribute__((ext_vector_type(4)));

__device__ __forceinline__ float sigm(float x){ return 1.0f/(1.0f+__expf(-x)); }

__device__ __forceinline__ u16 bf16_rne(float x){
  unsigned u = __float_as_uint(x);
  return (u16)((u + 0x7fffu + ((u>>16)&1u)) >> 16);
}
__device__ __forceinline__ float bf16_f(u16 h){
  return __uint_as_float(((unsigned)h)<<16);
}

// async 16B global -> LDS DMA
__device__ __forceinline__ void gload16(const void* g, void* l){
  __builtin_amdgcn_global_load_lds(
    reinterpret_cast<const __attribute__((address_space(1))) unsigned*>(
        reinterpret_cast<uintptr_t>(g)),
    reinterpret_cast<__attribute__((address_space(3))) unsigned*>(
        reinterpret_cast<uintptr_t>(l)),
    16, 0, 0);
}

// ---------------------------------------------------------------------------
// Weight prep: W[K][Nsrc] fp32 -> H/L[Ndst][K] bf16 hi/lo (transposed).
// ---------------------------------------------------------------------------
__global__ __launch_bounds__(256) void wprep_k(
    const float* __restrict__ W, u16* __restrict__ H, u16* __restrict__ L,
    int Nsrc, int Ndst, int K)
{
  __shared__ float T[32][33];
  int z = blockIdx.z;
  W += (size_t)z*K*Nsrc; H += (size_t)z*Ndst*K; L += (size_t)z*Ndst*K;
  int n0 = blockIdx.x*32, k0 = blockIdx.y*32;
  int tx = threadIdx.x&31, ty = threadIdx.x>>5;
  #pragma unroll
  for (int r=0;r<4;r++){
    int kk = ty+8*r, col = n0+tx;
    T[kk][tx] = (col<Nsrc) ? W[(size_t)(k0+kk)*Nsrc+col] : 0.f;
  }
  __syncthreads();
  #pragma unroll
  for (int r=0;r<4;r++){
    int nn = ty+8*r, n = n0+nn, k = k0+tx;
    if (n<Ndst){
      float f = T[tx][nn];
      u16 h = bf16_rne(f);
      H[(size_t)n*K+k] = h;
      L[(size_t)n*K+k] = bf16_rne(f - bf16_f(h));
    }
  }
}

// ---------------------------------------------------------------------------
// Unified MFMA GEMM, DMA-staged, double-buffered, counted-vmcnt pipeline
// (round-3 structure: proven best at this tile/shape).
// A: bf16 hi plane AH (+ lo plane AL for SPLIT==3), row-major [M][lda].
// W: pre-split planes WH/WL, row-major [N][ldw].
// Tile 128x128, BK=32, 4 waves, 4x4 of 16x16x32 MFMA.
// SPLIT: 3 = bf16x3 (fp32-like), 1 = plain bf16.
// EPI bits: 1=SiLU, 2=C+=v, 8=store bf16 u16, 16=atomicAdd f32,
//           32=scale by 0.5/3 (fractal stage-3 fused addscale).
// ---------------------------------------------------------------------------
template<int EPI, int SPLIT, int SPLITK>
__global__ __launch_bounds__(256) void gemm_u(
    const u16* __restrict__ AH, const u16* __restrict__ AL, int lda,
    const u16* __restrict__ WH, const u16* __restrict__ WL, int ldw,
    const float* __restrict__ bias, void* __restrict__ Cout,
    int N, int Kloop, size_t zA, size_t zW, size_t zB, size_t zC)
{
  constexpr int NPL = (SPLIT==3)?4:2;        // planes per buffer
  constexpr int NLD = (SPLIT==3)?8:4;        // DMA issues/thread/k-step
  __shared__ __align__(16) u16 smem[2*NPL*4096];

  const int z = blockIdx.z;
  const u16* ah = AH + (size_t)z*zA;
  const u16* bh = WH + (size_t)z*zW;
  const u16* al = nullptr;
  const u16* bl = nullptr;
  if constexpr (SPLIT==3){ al = AL + (size_t)z*zA; bl = WL + (size_t)z*zW; }

  const int tid  = threadIdx.x;
  const int m0 = blockIdx.y<<7, n0 = blockIdx.x<<7;
  const int wave = tid>>6, lane = tid&63;
  const int r = lane&15, q = lane>>4;
  const int wm = (wave&1)<<6, wn = (wave>>1)<<6;
  const int srow = tid>>2;        // 0..63 (row within 64-row half)
  const int scol = (tid&3)*8;     // u16 col offset (0,8,16,24)
  const int sdst = tid*8;         // u16 LDS offset of this thread's 16B

  const int nk = Kloop >> 5;

  auto STAGE = [&](int idx){
    u16* s = smem + (size_t)(idx&1)*NPL*4096;
    const int k0 = idx<<5;
    #pragma unroll
    for (int i=0;i<2;i++){
      const size_t gao = (size_t)(m0 + i*64 + srow)*lda + k0 + scol;
      const size_t gbo = (size_t)(n0 + i*64 + srow)*ldw + k0 + scol;
      const int lo = i*2048 + sdst;
      gload16(ah+gao, s+lo);
      gload16(bh+gbo, s+4096+lo);
      if constexpr (SPLIT==3){
        gload16(al+gao, s+2*4096+lo);
        gload16(bl+gbo, s+3*4096+lo);
      }
    }
  };

  f32x4 acc[4][4];
  #pragma unroll
  for (int i=0;i<4;i++)
    #pragma unroll
    for (int j=0;j<4;j++)
      #pragma unroll
      for (int t=0;t<4;t++) acc[i][j][t]=0.f;

  STAGE(0);
  if (nk > 1) STAGE(1);

  for (int idx = 0; idx < nk; idx++){
    // wait for buf[idx&1]'s loads only; keep next tile's NLD in flight
    if (idx+1 < nk) asm volatile("s_waitcnt vmcnt(%0)" :: "n"(NLD) : "memory");
    else            asm volatile("s_waitcnt vmcnt(0)" ::: "memory");
    __builtin_amdgcn_s_barrier();

    const u16* s = smem + (size_t)(idx&1)*NPL*4096;
    const u16* sA = s;
    const u16* sB = s + 4096;

    short8 aHf[4], bHf[4];
    #pragma unroll
    for (int i=0;i<4;i++) aHf[i] = *(const short8*)&sA[(wm + 16*i + r)*32 + q*8];
    #pragma unroll
    for (int j=0;j<4;j++) bHf[j] = *(const short8*)&sB[(wn + 16*j + r)*32 + q*8];
    short8 aLf[4], bLf[4];
    if constexpr (SPLIT==3){
      const u16* sAL = s + 2*4096;
      const u16* sBL = s + 3*4096;
      #pragma unroll
      for (int i=0;i<4;i++) aLf[i] = *(const short8*)&sAL[(wm + 16*i + r)*32 + q*8];
      #pragma unroll
      for (int j=0;j<4;j++) bLf[j] = *(const short8*)&sBL[(wn + 16*j + r)*32 + q*8];
    }
    // frags drained to regs before allowing overwrite of this buffer
    asm volatile("s_waitcnt lgkmcnt(0)" ::: "memory");
    __builtin_amdgcn_sched_barrier(0);
    __builtin_amdgcn_s_barrier();

    if (idx+2 < nk) STAGE(idx+2);   // overlaps MFMA below

    if constexpr (SPLIT==3){
      #pragma unroll
      for (int i=0;i<4;i++)
        #pragma unroll
        for (int j=0;j<4;j++){
          acc[i][j] = __builtin_amdgcn_mfma_f32_16x16x32_bf16(aHf[i], bHf[j], acc[i][j], 0,0,0);
          acc[i][j] = __builtin_amdgcn_mfma_f32_16x16x32_bf16(aHf[i], bLf[j], acc[i][j], 0,0,0);
          acc[i][j] = __builtin_amdgcn_mfma_f32_16x16x32_bf16(aLf[i], bHf[j], acc[i][j], 0,0,0);
        }
    } else {
      #pragma unroll
      for (int i=0;i<4;i++)
        #pragma unroll
        for (int j=0;j<4;j++)
          acc[i][j] = __builtin_amdgcn_mfma_f32_16x16x32_bf16(aHf[i], bHf[j], acc[i][j], 0,0,0);
    }
  }

  float* Cf = (float*)Cout + (size_t)z*zC;
  u16*   Cu = (u16*)Cout   + (size_t)z*zC;
  const float* bz = bias ? (bias + (size_t)z*zB) : bias;
  #pragma unroll
  for (int j=0;j<4;j++){
    int n_out = n0 + wn + 16*j + r;
    float bv = (bz && (!SPLITK || z==0)) ? bz[n_out] : 0.f;
    #pragma unroll
    for (int i=0;i<4;i++){
      #pragma unroll
      for (int reg=0;reg<4;reg++){
        int m_out = m0 + wm + 16*i + 4*q + reg;
        float v = acc[i][j][reg] + bv;
        if (EPI & 1)  v *= sigm(v);
        if (EPI & 32) v *= (0.5f/3.0f);
        size_t o = (size_t)m_out*N + n_out;
        if      (EPI & 16) atomicAdd(&Cf[o], v);
        else if (EPI & 8)  Cu[o] = bf16_rne(v);
        else if (EPI & 2)  Cf[o] += v;
        else               Cf[o] = v;
      }
    }
  }
}

// ---------------------------------------------------------------------------
// xproj GEMM: DBC[4096][36] = U[4096][1536] @ xw; pre-split xwT[48][1536].
// ---------------------------------------------------------------------------
__global__ __launch_bounds__(64) void xgemm_k(
    const float* __restrict__ A, const u16* __restrict__ XH,
    const u16* __restrict__ XL, float* __restrict__ DBC)
{
  int m0 = blockIdx.x*16;
  int lane = threadIdx.x;
  int r = lane&15, q = lane>>4;
  f32x4 acc[3];
  #pragma unroll
  for (int j=0;j<3;j++)
    #pragma unroll
    for (int t=0;t<4;t++) acc[j][t]=0.f;

  for (int k0 = 0; k0 < EDIM; k0 += 32){
    const float* ap = A + (size_t)(m0+r)*EDIM + k0 + q*8;
    float f[8];
    *(float4*)&f[0] = *(const float4*)(ap+0);
    *(float4*)&f[4] = *(const float4*)(ap+4);
    short8 ah, al;
    #pragma unroll
    for (int t=0;t<8;t++){
      u16 h = bf16_rne(f[t]);
      ah[t] = (short)h;
      al[t] = (short)bf16_rne(f[t]-bf16_f(h));
    }
    #pragma unroll
    for (int j=0;j<3;j++){
      size_t o = (size_t)(16*j+r)*EDIM + k0 + q*8;
      short8 bh = *(const short8*)&XH[o];
      short8 bl = *(const short8*)&XL[o];
      acc[j] = __builtin_amdgcn_mfma_f32_16x16x32_bf16(ah, bh, acc[j], 0,0,0);
      acc[j] = __builtin_amdgcn_mfma_f32_16x16x32_bf16(ah, bl, acc[j], 0,0,0);
      acc[j] = __builtin_amdgcn_mfma_f32_16x16x32_bf16(al, bh, acc[j], 0,0,0);
    }
  }
  #pragma unroll
  for (int j=0;j<3;j++){
    int n = 16*j + r;
    if (n < 36){
      #pragma unroll
      for (int reg=0;reg<4;reg++){
        int m = m0 + 4*q + reg;
        DBC[(size_t)m*36 + n] = acc[j][reg];
      }
    }
  }
}

// ---------------------------------------------------------------------------
__global__ __launch_bounds__(256) void embed_k(
    const int* __restrict__ ids, const float* __restrict__ tok,
    const float* __restrict__ pos, float* __restrict__ HS)
{
  int idx = blockIdx.x*256 + threadIdx.x;
  int h = idx % HDIM; int t = idx / HDIM;
  int lpos = t % LSEQ;
  int id = ids[t];
  HS[idx] = tok[id*HDIM + h] + pos[lpos*HDIM + h];
}

// ---------------------------------------------------------------------------
// PACK=1: write bf16 hi/lo planes (O1=H, O2=L). PACK=0: fp32 to O1.
template<int PACK>
__global__ __launch_bounds__(256) void ln_k(
    const float* __restrict__ X, const float* __restrict__ w,
    const float* __restrict__ b, void* __restrict__ O1, void* __restrict__ O2)
{
  int t = blockIdx.x;
  const float* x = X + (size_t)t*HDIM;
  float s=0.f, s2=0.f;
  for (int i=threadIdx.x; i<HDIM; i+=256){ float v=x[i]; s+=v; s2+=v*v; }
  #pragma unroll
  for (int off=32; off; off>>=1){ s += __shfl_down(s,off,64); s2 += __shfl_down(s2,off,64); }
  __shared__ float rs[4], rs2[4], mv[2];
  int lane = threadIdx.x & 63, wv = threadIdx.x >> 6;
  if (!lane){ rs[wv]=s; rs2[wv]=s2; }
  __syncthreads();
  if (!threadIdx.x){
    float a = rs[0]+rs[1]+rs[2]+rs[3];
    float c = rs2[0]+rs2[1]+rs2[2]+rs2[3];
    float m = a/HDIM;
    mv[0]=m; mv[1]=rsqrtf(c/HDIM - m*m + 1e-5f);
  }
  __syncthreads();
  float m = mv[0], r = mv[1];
  for (int i=threadIdx.x; i<HDIM; i+=256){
    float v = (x[i]-m)*r*w[i] + b[i];
    if (PACK){
      u16 h = bf16_rne(v);
      ((u16*)O1)[(size_t)t*HDIM+i] = h;
      ((u16*)O2)[(size_t)t*HDIM+i] = bf16_rne(v - bf16_f(h));
    } else {
      ((float*)O1)[(size_t)t*HDIM+i] = v;
    }
  }
}

// fp32 -> bf16 (hi only) convert, 4 elems/thread
__global__ __launch_bounds__(256) void cvt_k(
    const float* __restrict__ X, u16* __restrict__ O)
{
  int i = blockIdx.x*256 + threadIdx.x;
  float4 v = ((const float4*)X)[i];
  u16x4 o;
  o[0]=bf16_rne(v.x); o[1]=bf16_rne(v.y); o[2]=bf16_rne(v.z); o[3]=bf16_rne(v.w);
  ((u16x4*)O)[i] = o;
}

// ---------------------------------------------------------------------------
__global__ __launch_bounds__(256) void conv_silu_k(
    const float* __restrict__ PROJ, const float* __restrict__ cw,
    const float* __restrict__ cb, float* __restrict__ U)
{
  int idx = blockIdx.x*256 + threadIdx.x;
  int e = idx % EDIM; int t = idx / EDIM;
  int l = t % LSEQ; int tb = t - l;
  float acc = cb[e];
  #pragma unroll
  for (int j=0;j<4;j++){
    int tt = l + j - 3;
    if (tt >= 0) acc += PROJ[(size_t)(tb+tt)*(2*EDIM) + e] * cw[e*4+j];
  }
  U[idx] = acc * sigm(acc);
}

// ---------------------------------------------------------------------------
// Coalesced chunked scan: thread = (channel, chunk), 16 states in registers.
// ---------------------------------------------------------------------------
__global__ __launch_bounds__(256) void scanA_k(
    const float* __restrict__ U, const float* __restrict__ DBC,
    const float* __restrict__ Alog, const float* __restrict__ dtw,
    const float* __restrict__ dtb, float* __restrict__ PSP,
    float* __restrict__ PSS)
{
  const int CH = LSEQ/NCHK;
  int el = threadIdx.x & 63, jj = threadIdx.x >> 6;
  int ch = blockIdx.x*64 + el;
  int j  = blockIdx.y*4 + jj;
  int e = ch % EDIM, b = ch / EDIM;

  float a[16], P[16], S[16];
  #pragma unroll
  for (int n=0;n<16;n++){ a[n] = -__expf(Alog[e*NST+n]); P[n]=1.f; S[n]=0.f; }
  float w0=dtw[e], w1=dtw[EDIM+e], w2=dtw[2*EDIM+e], w3=dtw[3*EDIM+e];
  float db=dtb[e];
  size_t base=(size_t)b*LSEQ;

  for (int t=j*CH; t<j*CH+CH; t++){
    size_t tok = base+t;
    float4 d4 = *(const float4*)&DBC[tok*36];
    float4 B0 = *(const float4*)&DBC[tok*36+4];
    float4 B1 = *(const float4*)&DBC[tok*36+8];
    float4 B2 = *(const float4*)&DBC[tok*36+12];
    float4 B3 = *(const float4*)&DBC[tok*36+16];
    float dt = d4.x*w0 + d4.y*w1 + d4.z*w2 + d4.w*w3 + db;
    dt = (dt>20.f)?dt:log1pf(__expf(dt));
    float du = dt * U[tok*EDIM+e];
    float Bv[16];
    *(float4*)&Bv[0]=B0; *(float4*)&Bv[4]=B1; *(float4*)&Bv[8]=B2; *(float4*)&Bv[12]=B3;
    #pragma unroll
    for (int n=0;n<16;n++){
      float dA = __expf(dt*a[n]);
      P[n]*=dA; S[n]=S[n]*dA + du*Bv[n];
    }
  }
  #pragma unroll
  for (int n=0;n<16;n++){
    PSP[(size_t)(j*16+n)*NCH + ch] = P[n];
    PSS[(size_t)(j*16+n)*NCH + ch] = S[n];
  }
}

// Sequential combine over chunks; rewrites PSS in place with the INCOMING
// state of each chunk (consumed by scanC).
__global__ __launch_bounds__(256) void scanB_k(
    const float* __restrict__ PSP, float* __restrict__ PSS)
{
  int idx = blockIdx.x*256 + threadIdx.x;   // over NCH*16
  int n = idx / NCH, ch = idx % NCH;
  float hin = 0.f;
  #pragma unroll 4
  for (int jj=0;jj<NCHK;jj++){
    size_t o = (size_t)(jj*16+n)*NCH + ch;
    float p = PSP[o], s = PSS[o];
    PSS[o] = hin;
    hin = p*hin + s;
  }
}

__global__ __launch_bounds__(256) void scanC_k(
    const float* __restrict__ U, const float* __restrict__ DBC,
    const float* __restrict__ Alog, const float* __restrict__ dtw,
    const float* __restrict__ dtb, const float* __restrict__ HIN,
    const float* __restrict__ Dp, const float* __restrict__ PROJ,
    u16* __restrict__ YH, u16* __restrict__ YL)
{
  const int CH = LSEQ/NCHK;
  int el = threadIdx.x & 63, jj = threadIdx.x >> 6;
  int ch = blockIdx.x*64 + el;
  int j  = blockIdx.y*4 + jj;
  int e = ch % EDIM, b = ch / EDIM;

  float a[16], h[16];
  #pragma unroll
  for (int n=0;n<16;n++){
    a[n] = -__expf(Alog[e*NST+n]);
    h[n] = HIN[(size_t)(j*16+n)*NCH + ch];
  }
  float w0=dtw[e], w1=dtw[EDIM+e], w2=dtw[2*EDIM+e], w3=dtw[3*EDIM+e];
  float db=dtb[e], dcf=Dp[e];
  size_t base=(size_t)b*LSEQ;

  for (int t=j*CH; t<j*CH+CH; t++){
    size_t tok = base+t;
    float4 d4 = *(const float4*)&DBC[tok*36];
    float4 B0 = *(const float4*)&DBC[tok*36+4];
    float4 B1 = *(const float4*)&DBC[tok*36+8];
    float4 B2 = *(const float4*)&DBC[tok*36+12];
    float4 B3 = *(const float4*)&DBC[tok*36+16];
    float4 C0 = *(const float4*)&DBC[tok*36+20];
    float4 C1 = *(const float4*)&DBC[tok*36+24];
    float4 C2 = *(const float4*)&DBC[tok*36+28];
    float4 C3 = *(const float4*)&DBC[tok*36+32];
    float dt = d4.x*w0 + d4.y*w1 + d4.z*w2 + d4.w*w3 + db;
    dt = (dt>20.f)?dt:log1pf(__expf(dt));
    float u = U[tok*EDIM+e];
    float du = dt * u;
    float Bv[16], Cv[16];
    *(float4*)&Bv[0]=B0; *(float4*)&Bv[4]=B1; *(float4*)&Bv[8]=B2; *(float4*)&Bv[12]=B3;
    *(float4*)&Cv[0]=C0; *(float4*)&Cv[4]=C1; *(float4*)&Cv[8]=C2; *(float4*)&Cv[12]=C3;
    float y = 0.f;
    #pragma unroll
    for (int n=0;n<16;n++){
      float dA = __expf(dt*a[n]);
      h[n] = h[n]*dA + du*Bv[n];
      y += h[n]*Cv[n];
    }
    float g = PROJ[tok*(2*EDIM) + EDIM + e];
    float yv = (y + u*dcf)*sigm(g);
    u16 hh = bf16_rne(yv);
    YH[tok*EDIM + e] = hh;
    YL[tok*EDIM + e] = bf16_rne(yv - bf16_f(hh));
  }
}

// ---------------------------------------------------------------------------
extern "C" void kernel_launch(void* const* d_in, const int* in_sizes, int n_in,
                              void* d_out, int out_size, void* d_ws, size_t ws_size,
                              hipStream_t stream)
{
  const int*   ids      = (const int*)d_in[0];
  const float* tok_emb  = (const float*)d_in[1];
  const float* pos_emb  = (const float*)d_in[2];
  const float* ln_w     = (const float*)d_in[3];
  const float* ln_b     = (const float*)d_in[4];
  const float* in_w     = (const float*)d_in[5];
  const float* in_b     = (const float*)d_in[6];
  const float* conv_w   = (const float*)d_in[7];
  const float* conv_b   = (const float*)d_in[8];
  const float* xproj_w  = (const float*)d_in[9];
  const float* dt_w     = (const float*)d_in[10];
  const float* dt_b     = (const float*)d_in[11];
  const float* A_log    = (const float*)d_in[12];
  const float* Dp       = (const float*)d_in[13];
  const float* out_w    = (const float*)d_in[14];
  const float* out_b    = (const float*)d_in[15];
  const float* frac_w   = (const float*)d_in[16];
  const float* frac_b   = (const float*)d_in[17];
  const float* fln_w    = (const float*)d_in[18];
  const float* fln_b    = (const float*)d_in[19];

  // ---- workspace map
  const size_t F_HS   = (size_t)BLTOK*HDIM;      // 3,145,728 floats
  const size_t F_PROJ = (size_t)BLTOK*2*EDIM;    // 12,582,912
  const size_t F_R1   = (size_t)BLTOK*EDIM;      //  6,291,456
  float* HS   = (float*)d_ws;
  float* PROJ = HS   + F_HS;
  float* R1   = PROJ + F_PROJ;                   // XH/XL, then U
  float* DBC  = R1   + F_R1;
  u16* W16  = (u16*)(DBC + (size_t)BLTOK*36);
  u16* inH  = W16;
  u16* inL  = inH  + (size_t)2359296;
  u16* outH = inL  + (size_t)2359296;
  u16* outL = outH + (size_t)1179648;
  u16* frH  = outL + (size_t)1179648;
  u16* frL  = frH  + (size_t)1769472;
  u16* xH   = frL  + (size_t)1769472;
  u16* xL   = xH   + (size_t)73728;
  float* PSP = (float*)(xL + (size_t)73728);
  float* PSS = PSP + (size_t)NCHK*16*NCH;        // 12.6 MB each
  u16* YH  = (u16*)(PSS + (size_t)NCHK*16*NCH);  // 4096x1536 u16
  u16* YL  = YH + (size_t)BLTOK*EDIM;
  // aliases
  u16*   XH  = (u16*)R1;                         // LN hi plane (dead before U)
  u16*   XL  = XH + F_HS;                        // LN lo plane
  float* U   = R1;                               // fp32 conv out (overwrites X)
  u16*   HSB = (u16*)PSP;                        // bf16(HS), PSP dead post-scanB
  u16*   S1  = (u16*)(PROJ + 3*F_HS);            // stage1 out, 3*F_HS u16
  u16*   S2  = S1 + 3*F_HS;                      // stage2 out, 3*F_HS u16

  embed_k<<<(BLTOK*HDIM)/256, 256, 0, stream>>>(ids, tok_emb, pos_emb, HS);

  const size_t zWf = (size_t)HDIM*HDIM;
  for (int l = 0; l < NLAYER; l++){
    wprep_k<<<dim3(3072/32, 768/32), 256, 0, stream>>>(
        in_w + (size_t)l*HDIM*2*EDIM, inH, inL, 2*EDIM, 2*EDIM, HDIM);
    wprep_k<<<dim3(768/32, 1536/32), 256, 0, stream>>>(
        out_w + (size_t)l*EDIM*HDIM, outH, outL, HDIM, HDIM, EDIM);
    wprep_k<<<dim3(768/32, 768/32, 3), 256, 0, stream>>>(
        frac_w + (size_t)l*3*HDIM*HDIM, frH, frL, HDIM, HDIM, HDIM);
    wprep_k<<<dim3(2, 1536/32), 256, 0, stream>>>(
        xproj_w + (size_t)l*EDIM*36, xH, xL, 36, 48, EDIM);

    // LN -> bf16 hi/lo planes
    ln_k<1><<<BLTOK, 256, 0, stream>>>(HS, ln_w + l*HDIM, ln_b + l*HDIM, XH, XL);

    // proj = LN(hs) @ in_w + in_b   [4096 x 768 -> 3072], bf16x3
    gemm_u<0,3,0><<<dim3(24, 32), 256, 0, stream>>>(
        XH, XL, HDIM, inH, inL, HDIM, in_b + l*2*EDIM, PROJ,
        2*EDIM, HDIM, 0,0,0,0);

    conv_silu_k<<<(BLTOK*EDIM)/256, 256, 0, stream>>>(
        PROJ, conv_w + l*EDIM*4, conv_b + l*EDIM, U);

    // dbc = u @ xproj_w
    xgemm_k<<<BLTOK/16, 64, 0, stream>>>(U, xH, xL, DBC);

    // selective scan (coalesced 3-phase), Y -> bf16 hi/lo planes
    scanA_k<<<dim3(NCH/64, NCHK/4), 256, 0, stream>>>(
        U, DBC, A_log + (size_t)l*EDIM*NST, dt_w + (size_t)l*4*EDIM,
        dt_b + (size_t)l*EDIM, PSP, PSS);
    scanB_k<<<(NCH*16)/256, 256, 0, stream>>>(PSP, PSS);
    scanC_k<<<dim3(NCH/64, NCHK/4), 256, 0, stream>>>(
        U, DBC, A_log + (size_t)l*EDIM*NST, dt_w + (size_t)l*4*EDIM,
        dt_b + (size_t)l*EDIM, PSS, Dp + (size_t)l*EDIM, PROJ, YH, YL);

    // hs += y @ out_w + out_b  [4096 x 1536 -> 768], bf16x3, split-K=2, atomic
    gemm_u<16,3,1><<<dim3(6, 32, 2), 256, 0, stream>>>(
        YH, YL, EDIM, outH, outL, EDIM, out_b + l*HDIM, HS,
        HDIM, EDIM/2, /*zA*/EDIM/2, /*zW*/EDIM/2, 0, 0);

    // bf16 copy of HS for fractal stage1 A-operand
    cvt_k<<<(BLTOK*HDIM)/1024, 256, 0, stream>>>(HS, HSB);

    // fractal: plain bf16 (error attenuated /6), 3 z-batched stages;
    // stage 3 fuses the addscale: HS += silu(.)*(0.5/3) via atomicAdd (zC=0)
    gemm_u<9,1,0><<<dim3(6, 32, 3), 256, 0, stream>>>(
        HSB, nullptr, HDIM, frH, frL, HDIM, frac_b + (size_t)l*3*HDIM, S1,
        HDIM, HDIM, 0, zWf, HDIM, F_HS);
    gemm_u<9,1,0><<<dim3(6, 32, 3), 256, 0, stream>>>(
        S1, nullptr, HDIM, frH, frL, HDIM, frac_b + (size_t)l*3*HDIM, S2,
        HDIM, HDIM, F_HS, zWf, HDIM, F_HS);
    gemm_u<1|16|32,1,0><<<dim3(6, 32, 3), 256, 0, stream>>>(
        S2, nullptr, HDIM, frH, frL, HDIM, frac_b + (size_t)l*3*HDIM, HS,
        HDIM, HDIM, F_HS, zWf, HDIM, 0);
  }

  ln_k<0><<<BLTOK, 256, 0, stream>>>(HS, fln_w, fln_b, (float*)d_out, nullptr);
}

// Round 7
// 3547.305 us; speedup vs baseline: 1.1773x; 1.0946x over previous
//
#include <hip/hip_runtime.h>
#include <hip/hip_bf16.h>
#include <stdint.h>

#define NLAYER 8
#define HDIM   768
#define EDIM   1536
#define NST    16
#define LSEQ   2048
#define BATCH  2
#define BLTOK  (BATCH*LSEQ)   /* 4096 tokens */
#define NCH    (BATCH*EDIM)   /* 3072 scan channels */
#define NCHK   64             /* scan time chunks */

typedef unsigned short u16;
typedef short  short8  __attribute__((ext_vector_type(8)));
typedef float  f32x4   __attribute__((ext_vector_type(4)));
typedef unsigned short u16x4 __attribute__((ext_vector_type(4)));

__device__ __forceinline__ float sigm(float x){ return 1.0f/(1.0f+__expf(-x)); }

__device__ __forceinline__ u16 bf16_rne(float x){
  unsigned u = __float_as_uint(x);
  return (u16)((u + 0x7fffu + ((u>>16)&1u)) >> 16);
}
__device__ __forceinline__ float bf16_f(u16 h){
  return __uint_as_float(((unsigned)h)<<16);
}

// async 16B global -> LDS DMA
__device__ __forceinline__ void gload16(const void* g, void* l){
  __builtin_amdgcn_global_load_lds(
    reinterpret_cast<const __attribute__((address_space(1))) unsigned*>(
        reinterpret_cast<uintptr_t>(g)),
    reinterpret_cast<__attribute__((address_space(3))) unsigned*>(
        reinterpret_cast<uintptr_t>(l)),
    16, 0, 0);
}

// ---------------------------------------------------------------------------
// Weight prep: W[K][Nsrc] fp32 -> H/L[Ndst][K] bf16 hi/lo (transposed).
// ---------------------------------------------------------------------------
__global__ __launch_bounds__(256) void wprep_k(
    const float* __restrict__ W, u16* __restrict__ H, u16* __restrict__ L,
    int Nsrc, int Ndst, int K)
{
  __shared__ float T[32][33];
  int z = blockIdx.z;
  W += (size_t)z*K*Nsrc; H += (size_t)z*Ndst*K; L += (size_t)z*Ndst*K;
  int n0 = blockIdx.x*32, k0 = blockIdx.y*32;
  int tx = threadIdx.x&31, ty = threadIdx.x>>5;
  #pragma unroll
  for (int r=0;r<4;r++){
    int kk = ty+8*r, col = n0+tx;
    T[kk][tx] = (col<Nsrc) ? W[(size_t)(k0+kk)*Nsrc+col] : 0.f;
  }
  __syncthreads();
  #pragma unroll
  for (int r=0;r<4;r++){
    int nn = ty+8*r, n = n0+nn, k = k0+tx;
    if (n<Ndst){
      float f = T[tx][nn];
      u16 h = bf16_rne(f);
      H[(size_t)n*K+k] = h;
      L[(size_t)n*K+k] = bf16_rne(f - bf16_f(h));
    }
  }
}

// ---------------------------------------------------------------------------
// Unified MFMA GEMM, DMA-staged, double-buffered, counted-vmcnt pipeline
// (round-3 structure: proven best at this tile/shape).
// SPLIT: 3 = bf16x3 (fp32-like), 1 = plain bf16.
// EPI bits: 1=SiLU, 2=C+=v, 8=store bf16 u16, 16=atomicAdd f32,
//           32=scale by 0.5/3 (fractal stage-3 fused addscale).
// ---------------------------------------------------------------------------
template<int EPI, int SPLIT, int SPLITK>
__global__ __launch_bounds__(256) void gemm_u(
    const u16* __restrict__ AH, const u16* __restrict__ AL, int lda,
    const u16* __restrict__ WH, const u16* __restrict__ WL, int ldw,
    const float* __restrict__ bias, void* __restrict__ Cout,
    int N, int Kloop, size_t zA, size_t zW, size_t zB, size_t zC)
{
  constexpr int NPL = (SPLIT==3)?4:2;        // planes per buffer
  constexpr int NLD = (SPLIT==3)?8:4;        // DMA issues/thread/k-step
  __shared__ __align__(16) u16 smem[2*NPL*4096];

  const int z = blockIdx.z;
  const u16* ah = AH + (size_t)z*zA;
  const u16* bh = WH + (size_t)z*zW;
  const u16* al = nullptr;
  const u16* bl = nullptr;
  if constexpr (SPLIT==3){ al = AL + (size_t)z*zA; bl = WL + (size_t)z*zW; }

  const int tid  = threadIdx.x;
  const int m0 = blockIdx.y<<7, n0 = blockIdx.x<<7;
  const int wave = tid>>6, lane = tid&63;
  const int r = lane&15, q = lane>>4;
  const int wm = (wave&1)<<6, wn = (wave>>1)<<6;
  const int srow = tid>>2;        // 0..63 (row within 64-row half)
  const int scol = (tid&3)*8;     // u16 col offset (0,8,16,24)
  const int sdst = tid*8;         // u16 LDS offset of this thread's 16B

  const int nk = Kloop >> 5;

  auto STAGE = [&](int idx){
    u16* s = smem + (size_t)(idx&1)*NPL*4096;
    const int k0 = idx<<5;
    #pragma unroll
    for (int i=0;i<2;i++){
      const size_t gao = (size_t)(m0 + i*64 + srow)*lda + k0 + scol;
      const size_t gbo = (size_t)(n0 + i*64 + srow)*ldw + k0 + scol;
      const int lo = i*2048 + sdst;
      gload16(ah+gao, s+lo);
      gload16(bh+gbo, s+4096+lo);
      if constexpr (SPLIT==3){
        gload16(al+gao, s+2*4096+lo);
        gload16(bl+gbo, s+3*4096+lo);
      }
    }
  };

  f32x4 acc[4][4];
  #pragma unroll
  for (int i=0;i<4;i++)
    #pragma unroll
    for (int j=0;j<4;j++)
      #pragma unroll
      for (int t=0;t<4;t++) acc[i][j][t]=0.f;

  STAGE(0);
  if (nk > 1) STAGE(1);

  for (int idx = 0; idx < nk; idx++){
    // wait for buf[idx&1]'s loads only; keep next tile's NLD in flight
    if (idx+1 < nk) asm volatile("s_waitcnt vmcnt(%0)" :: "n"(NLD) : "memory");
    else            asm volatile("s_waitcnt vmcnt(0)" ::: "memory");
    __builtin_amdgcn_s_barrier();

    const u16* s = smem + (size_t)(idx&1)*NPL*4096;
    const u16* sA = s;
    const u16* sB = s + 4096;

    short8 aHf[4], bHf[4];
    #pragma unroll
    for (int i=0;i<4;i++) aHf[i] = *(const short8*)&sA[(wm + 16*i + r)*32 + q*8];
    #pragma unroll
    for (int j=0;j<4;j++) bHf[j] = *(const short8*)&sB[(wn + 16*j + r)*32 + q*8];
    short8 aLf[4], bLf[4];
    if constexpr (SPLIT==3){
      const u16* sAL = s + 2*4096;
      const u16* sBL = s + 3*4096;
      #pragma unroll
      for (int i=0;i<4;i++) aLf[i] = *(const short8*)&sAL[(wm + 16*i + r)*32 + q*8];
      #pragma unroll
      for (int j=0;j<4;j++) bLf[j] = *(const short8*)&sBL[(wn + 16*j + r)*32 + q*8];
    }
    // frags drained to regs before allowing overwrite of this buffer
    asm volatile("s_waitcnt lgkmcnt(0)" ::: "memory");
    __builtin_amdgcn_sched_barrier(0);
    __builtin_amdgcn_s_barrier();

    if (idx+2 < nk) STAGE(idx+2);   // overlaps MFMA below

    if constexpr (SPLIT==3){
      #pragma unroll
      for (int i=0;i<4;i++)
        #pragma unroll
        for (int j=0;j<4;j++){
          acc[i][j] = __builtin_amdgcn_mfma_f32_16x16x32_bf16(aHf[i], bHf[j], acc[i][j], 0,0,0);
          acc[i][j] = __builtin_amdgcn_mfma_f32_16x16x32_bf16(aHf[i], bLf[j], acc[i][j], 0,0,0);
          acc[i][j] = __builtin_amdgcn_mfma_f32_16x16x32_bf16(aLf[i], bHf[j], acc[i][j], 0,0,0);
        }
    } else {
      #pragma unroll
      for (int i=0;i<4;i++)
        #pragma unroll
        for (int j=0;j<4;j++)
          acc[i][j] = __builtin_amdgcn_mfma_f32_16x16x32_bf16(aHf[i], bHf[j], acc[i][j], 0,0,0);
    }
  }

  float* Cf = (float*)Cout + (size_t)z*zC;
  u16*   Cu = (u16*)Cout   + (size_t)z*zC;
  const float* bz = bias ? (bias + (size_t)z*zB) : bias;
  #pragma unroll
  for (int j=0;j<4;j++){
    int n_out = n0 + wn + 16*j + r;
    float bv = (bz && (!SPLITK || z==0)) ? bz[n_out] : 0.f;
    #pragma unroll
    for (int i=0;i<4;i++){
      #pragma unroll
      for (int reg=0;reg<4;reg++){
        int m_out = m0 + wm + 16*i + 4*q + reg;
        float v = acc[i][j][reg] + bv;
        if (EPI & 1)  v *= sigm(v);
        if (EPI & 32) v *= (0.5f/3.0f);
        size_t o = (size_t)m_out*N + n_out;
        if      (EPI & 16) atomicAdd(&Cf[o], v);
        else if (EPI & 8)  Cu[o] = bf16_rne(v);
        else if (EPI & 2)  Cf[o] += v;
        else               Cf[o] = v;
      }
    }
  }
}

// ---------------------------------------------------------------------------
// xproj GEMM: DBC[4096][36] = U[4096][1536] @ xw; pre-split xwT[48][1536].
// Split-K x4: 256 threads, wave w covers K in [w*384,(w+1)*384); LDS reduce.
// (was 64-thread blocks = 0.25 waves/SIMD, latency-bound)
// ---------------------------------------------------------------------------
__global__ __launch_bounds__(256) void xgemm_k(
    const float* __restrict__ A, const u16* __restrict__ XH,
    const u16* __restrict__ XL, float* __restrict__ DBC)
{
  __shared__ f32x4 red[3][4][64];   // 12 KB
  int m0 = blockIdx.x*16;
  int wv = threadIdx.x>>6, lane = threadIdx.x&63;
  int r = lane&15, q = lane>>4;
  f32x4 acc[3];
  #pragma unroll
  for (int j=0;j<3;j++)
    #pragma unroll
    for (int t=0;t<4;t++) acc[j][t]=0.f;

  const int KW = EDIM/4;           // 384
  const int kend = (wv+1)*KW;
  for (int k0 = wv*KW; k0 < kend; k0 += 32){
    const float* ap = A + (size_t)(m0+r)*EDIM + k0 + q*8;
    float f[8];
    *(float4*)&f[0] = *(const float4*)(ap+0);
    *(float4*)&f[4] = *(const float4*)(ap+4);
    short8 ah, al;
    #pragma unroll
    for (int t=0;t<8;t++){
      u16 h = bf16_rne(f[t]);
      ah[t] = (short)h;
      al[t] = (short)bf16_rne(f[t]-bf16_f(h));
    }
    #pragma unroll
    for (int j=0;j<3;j++){
      size_t o = (size_t)(16*j+r)*EDIM + k0 + q*8;
      short8 bh = *(const short8*)&XH[o];
      short8 bl = *(const short8*)&XL[o];
      acc[j] = __builtin_amdgcn_mfma_f32_16x16x32_bf16(ah, bh, acc[j], 0,0,0);
      acc[j] = __builtin_amdgcn_mfma_f32_16x16x32_bf16(ah, bl, acc[j], 0,0,0);
      acc[j] = __builtin_amdgcn_mfma_f32_16x16x32_bf16(al, bh, acc[j], 0,0,0);
    }
  }
  #pragma unroll
  for (int j=0;j<3;j++) red[j][wv][lane] = acc[j];
  __syncthreads();
  if (wv == 0){
    #pragma unroll
    for (int j=0;j<3;j++){
      f32x4 s = red[j][0][lane];
      s += red[j][1][lane];
      s += red[j][2][lane];
      s += red[j][3][lane];
      int n = 16*j + r;
      if (n < 36){
        #pragma unroll
        for (int reg=0;reg<4;reg++){
          int m = m0 + 4*q + reg;
          DBC[(size_t)m*36 + n] = s[reg];
        }
      }
    }
  }
}

// ---------------------------------------------------------------------------
__global__ __launch_bounds__(256) void embed_k(
    const int* __restrict__ ids, const float* __restrict__ tok,
    const float* __restrict__ pos, float* __restrict__ HS)
{
  int idx = blockIdx.x*256 + threadIdx.x;
  int h = idx % HDIM; int t = idx / HDIM;
  int lpos = t % LSEQ;
  int id = ids[t];
  HS[idx] = tok[id*HDIM + h] + pos[lpos*HDIM + h];
}

// ---------------------------------------------------------------------------
// Wave-per-token LN (no barriers, no LDS). 4 tokens/block.
// PACK=1: write bf16 hi/lo planes (O1=H, O2=L). PACK=0: fp32 to O1.
template<int PACK>
__global__ __launch_bounds__(256) void ln_k(
    const float* __restrict__ X, const float* __restrict__ w,
    const float* __restrict__ b, void* __restrict__ O1, void* __restrict__ O2)
{
  int wv = threadIdx.x>>6, lane = threadIdx.x&63;
  int t = blockIdx.x*4 + wv;
  const float* x = X + (size_t)t*HDIM;
  float v[12];
  float s=0.f, s2=0.f;
  #pragma unroll
  for (int k=0;k<12;k++){
    v[k] = x[lane + 64*k];
    s += v[k]; s2 += v[k]*v[k];
  }
  #pragma unroll
  for (int off=32; off; off>>=1){
    s  += __shfl_xor(s,  off, 64);
    s2 += __shfl_xor(s2, off, 64);
  }
  float m = s/HDIM, rr = rsqrtf(s2/HDIM - m*m + 1e-5f);
  #pragma unroll
  for (int k=0;k<12;k++){
    int i = lane + 64*k;
    float o = (v[k]-m)*rr*w[i] + b[i];
    if (PACK){
      u16 h = bf16_rne(o);
      ((u16*)O1)[(size_t)t*HDIM+i] = h;
      ((u16*)O2)[(size_t)t*HDIM+i] = bf16_rne(o - bf16_f(h));
    } else {
      ((float*)O1)[(size_t)t*HDIM+i] = o;
    }
  }
}

// fp32 -> bf16 (hi only) convert, 4 elems/thread
__global__ __launch_bounds__(256) void cvt_k(
    const float* __restrict__ X, u16* __restrict__ O)
{
  int i = blockIdx.x*256 + threadIdx.x;
  float4 v = ((const float4*)X)[i];
  u16x4 o;
  o[0]=bf16_rne(v.x); o[1]=bf16_rne(v.y); o[2]=bf16_rne(v.z); o[3]=bf16_rne(v.w);
  ((u16x4*)O)[i] = o;
}

// ---------------------------------------------------------------------------
__global__ __launch_bounds__(256) void conv_silu_k(
    const float* __restrict__ PROJ, const float* __restrict__ cw,
    const float* __restrict__ cb, float* __restrict__ U)
{
  int idx = blockIdx.x*256 + threadIdx.x;
  int e = idx % EDIM; int t = idx / EDIM;
  int l = t % LSEQ; int tb = t - l;
  float acc = cb[e];
  #pragma unroll
  for (int j=0;j<4;j++){
    int tt = l + j - 3;
    if (tt >= 0) acc += PROJ[(size_t)(tb+tt)*(2*EDIM) + e] * cw[e*4+j];
  }
  U[idx] = acc * sigm(acc);
}

// ---------------------------------------------------------------------------
// Coalesced chunked scan: thread = (channel, chunk), 16 states in registers.
// ---------------------------------------------------------------------------
__global__ __launch_bounds__(256) void scanA_k(
    const float* __restrict__ U, const float* __restrict__ DBC,
    const float* __restrict__ Alog, const float* __restrict__ dtw,
    const float* __restrict__ dtb, float* __restrict__ PSP,
    float* __restrict__ PSS)
{
  const int CH = LSEQ/NCHK;
  int el = threadIdx.x & 63, jj = threadIdx.x >> 6;
  int ch = blockIdx.x*64 + el;
  int j  = blockIdx.y*4 + jj;
  int e = ch % EDIM, b = ch / EDIM;

  float a[16], P[16], S[16];
  #pragma unroll
  for (int n=0;n<16;n++){ a[n] = -__expf(Alog[e*NST+n]); P[n]=1.f; S[n]=0.f; }
  float w0=dtw[e], w1=dtw[EDIM+e], w2=dtw[2*EDIM+e], w3=dtw[3*EDIM+e];
  float db=dtb[e];
  size_t base=(size_t)b*LSEQ;

  for (int t=j*CH; t<j*CH+CH; t++){
    size_t tok = base+t;
    float4 d4 = *(const float4*)&DBC[tok*36];
    float4 B0 = *(const float4*)&DBC[tok*36+4];
    float4 B1 = *(const float4*)&DBC[tok*36+8];
    float4 B2 = *(const float4*)&DBC[tok*36+12];
    float4 B3 = *(const float4*)&DBC[tok*36+16];
    float dt = d4.x*w0 + d4.y*w1 + d4.z*w2 + d4.w*w3 + db;
    dt = (dt>20.f)?dt:log1pf(__expf(dt));
    float du = dt * U[tok*EDIM+e];
    float Bv[16];
    *(float4*)&Bv[0]=B0; *(float4*)&Bv[4]=B1; *(float4*)&Bv[8]=B2; *(float4*)&Bv[12]=B3;
    #pragma unroll
    for (int n=0;n<16;n++){
      float dA = __expf(dt*a[n]);
      P[n]*=dA; S[n]=S[n]*dA + du*Bv[n];
    }
  }
  #pragma unroll
  for (int n=0;n<16;n++){
    PSP[(size_t)(j*16+n)*NCH + ch] = P[n];
    PSS[(size_t)(j*16+n)*NCH + ch] = S[n];
  }
}

// Sequential combine over chunks; rewrites PSS in place with the INCOMING
// state of each chunk (consumed by scanC).
__global__ __launch_bounds__(256) void scanB_k(
    const float* __restrict__ PSP, float* __restrict__ PSS)
{
  int idx = blockIdx.x*256 + threadIdx.x;   // over NCH*16
  int n = idx / NCH, ch = idx % NCH;
  float hin = 0.f;
  #pragma unroll 4
  for (int jj=0;jj<NCHK;jj++){
    size_t o = (size_t)(jj*16+n)*NCH + ch;
    float p = PSP[o], s = PSS[o];
    PSS[o] = hin;
    hin = p*hin + s;
  }
}

__global__ __launch_bounds__(256) void scanC_k(
    const float* __restrict__ U, const float* __restrict__ DBC,
    const float* __restrict__ Alog, const float* __restrict__ dtw,
    const float* __restrict__ dtb, const float* __restrict__ HIN,
    const float* __restrict__ Dp, const float* __restrict__ PROJ,
    u16* __restrict__ YH, u16* __restrict__ YL)
{
  const int CH = LSEQ/NCHK;
  int el = threadIdx.x & 63, jj = threadIdx.x >> 6;
  int ch = blockIdx.x*64 + el;
  int j  = blockIdx.y*4 + jj;
  int e = ch % EDIM, b = ch / EDIM;

  float a[16], h[16];
  #pragma unroll
  for (int n=0;n<16;n++){
    a[n] = -__expf(Alog[e*NST+n]);
    h[n] = HIN[(size_t)(j*16+n)*NCH + ch];
  }
  float w0=dtw[e], w1=dtw[EDIM+e], w2=dtw[2*EDIM+e], w3=dtw[3*EDIM+e];
  float db=dtb[e], dcf=Dp[e];
  size_t base=(size_t)b*LSEQ;

  for (int t=j*CH; t<j*CH+CH; t++){
    size_t tok = base+t;
    float4 d4 = *(const float4*)&DBC[tok*36];
    float4 B0 = *(const float4*)&DBC[tok*36+4];
    float4 B1 = *(const float4*)&DBC[tok*36+8];
    float4 B2 = *(const float4*)&DBC[tok*36+12];
    float4 B3 = *(const float4*)&DBC[tok*36+16];
    float4 C0 = *(const float4*)&DBC[tok*36+20];
    float4 C1 = *(const float4*)&DBC[tok*36+24];
    float4 C2 = *(const float4*)&DBC[tok*36+28];
    float4 C3 = *(const float4*)&DBC[tok*36+32];
    float dt = d4.x*w0 + d4.y*w1 + d4.z*w2 + d4.w*w3 + db;
    dt = (dt>20.f)?dt:log1pf(__expf(dt));
    float u = U[tok*EDIM+e];
    float du = dt * u;
    float Bv[16], Cv[16];
    *(float4*)&Bv[0]=B0; *(float4*)&Bv[4]=B1; *(float4*)&Bv[8]=B2; *(float4*)&Bv[12]=B3;
    *(float4*)&Cv[0]=C0; *(float4*)&Cv[4]=C1; *(float4*)&Cv[8]=C2; *(float4*)&Cv[12]=C3;
    float y = 0.f;
    #pragma unroll
    for (int n=0;n<16;n++){
      float dA = __expf(dt*a[n]);
      h[n] = h[n]*dA + du*Bv[n];
      y += h[n]*Cv[n];
    }
    float g = PROJ[tok*(2*EDIM) + EDIM + e];
    float yv = (y + u*dcf)*sigm(g);
    u16 hh = bf16_rne(yv);
    YH[tok*EDIM + e] = hh;
    YL[tok*EDIM + e] = bf16_rne(yv - bf16_f(hh));
  }
}

// ---------------------------------------------------------------------------
extern "C" void kernel_launch(void* const* d_in, const int* in_sizes, int n_in,
                              void* d_out, int out_size, void* d_ws, size_t ws_size,
                              hipStream_t stream)
{
  const int*   ids      = (const int*)d_in[0];
  const float* tok_emb  = (const float*)d_in[1];
  const float* pos_emb  = (const float*)d_in[2];
  const float* ln_w     = (const float*)d_in[3];
  const float* ln_b     = (const float*)d_in[4];
  const float* in_w     = (const float*)d_in[5];
  const float* in_b     = (const float*)d_in[6];
  const float* conv_w   = (const float*)d_in[7];
  const float* conv_b   = (const float*)d_in[8];
  const float* xproj_w  = (const float*)d_in[9];
  const float* dt_w     = (const float*)d_in[10];
  const float* dt_b     = (const float*)d_in[11];
  const float* A_log    = (const float*)d_in[12];
  const float* Dp       = (const float*)d_in[13];
  const float* out_w    = (const float*)d_in[14];
  const float* out_b    = (const float*)d_in[15];
  const float* frac_w   = (const float*)d_in[16];
  const float* frac_b   = (const float*)d_in[17];
  const float* fln_w    = (const float*)d_in[18];
  const float* fln_b    = (const float*)d_in[19];

  // ---- workspace map
  const size_t F_HS   = (size_t)BLTOK*HDIM;      // 3,145,728 floats
  const size_t F_PROJ = (size_t)BLTOK*2*EDIM;    // 12,582,912
  const size_t F_R1   = (size_t)BLTOK*EDIM;      //  6,291,456
  float* HS   = (float*)d_ws;
  float* PROJ = HS   + F_HS;
  float* R1   = PROJ + F_PROJ;                   // XH/XL, then U
  float* DBC  = R1   + F_R1;
  u16* W16  = (u16*)(DBC + (size_t)BLTOK*36);
  u16* inH  = W16;
  u16* inL  = inH  + (size_t)2359296;
  u16* outH = inL  + (size_t)2359296;
  u16* outL = outH + (size_t)1179648;
  u16* frH  = outL + (size_t)1179648;
  u16* frL  = frH  + (size_t)1769472;
  u16* xH   = frL  + (size_t)1769472;
  u16* xL   = xH   + (size_t)73728;
  float* PSP = (float*)(xL + (size_t)73728);
  float* PSS = PSP + (size_t)NCHK*16*NCH;        // 12.6 MB each
  u16* YH  = (u16*)(PSS + (size_t)NCHK*16*NCH);  // 4096x1536 u16
  u16* YL  = YH + (size_t)BLTOK*EDIM;
  // aliases
  u16*   XH  = (u16*)R1;                         // LN hi plane (dead before U)
  u16*   XL  = XH + F_HS;                        // LN lo plane
  float* U   = R1;                               // fp32 conv out (overwrites X)
  u16*   HSB = (u16*)PSP;                        // bf16(HS), PSP dead post-scanB
  u16*   S1  = (u16*)(PROJ + 3*F_HS);            // stage1 out, 3*F_HS u16
  u16*   S2  = S1 + 3*F_HS;                      // stage2 out, 3*F_HS u16

  embed_k<<<(BLTOK*HDIM)/256, 256, 0, stream>>>(ids, tok_emb, pos_emb, HS);

  const size_t zWf = (size_t)HDIM*HDIM;
  for (int l = 0; l < NLAYER; l++){
    wprep_k<<<dim3(3072/32, 768/32), 256, 0, stream>>>(
        in_w + (size_t)l*HDIM*2*EDIM, inH, inL, 2*EDIM, 2*EDIM, HDIM);
    wprep_k<<<dim3(768/32, 1536/32), 256, 0, stream>>>(
        out_w + (size_t)l*EDIM*HDIM, outH, outL, HDIM, HDIM, EDIM);
    wprep_k<<<dim3(768/32, 768/32, 3), 256, 0, stream>>>(
        frac_w + (size_t)l*3*HDIM*HDIM, frH, frL, HDIM, HDIM, HDIM);
    wprep_k<<<dim3(2, 1536/32), 256, 0, stream>>>(
        xproj_w + (size_t)l*EDIM*36, xH, xL, 36, 48, EDIM);

    // LN -> bf16 hi/lo planes (wave-per-token)
    ln_k<1><<<BLTOK/4, 256, 0, stream>>>(HS, ln_w + l*HDIM, ln_b + l*HDIM, XH, XL);

    // proj = LN(hs) @ in_w + in_b   [4096 x 768 -> 3072], bf16x3
    gemm_u<0,3,0><<<dim3(24, 32), 256, 0, stream>>>(
        XH, XL, HDIM, inH, inL, HDIM, in_b + l*2*EDIM, PROJ,
        2*EDIM, HDIM, 0,0,0,0);

    conv_silu_k<<<(BLTOK*EDIM)/256, 256, 0, stream>>>(
        PROJ, conv_w + l*EDIM*4, conv_b + l*EDIM, U);

    // dbc = u @ xproj_w (split-K x4)
    xgemm_k<<<BLTOK/16, 256, 0, stream>>>(U, xH, xL, DBC);

    // selective scan (coalesced 3-phase), Y -> bf16 hi/lo planes
    scanA_k<<<dim3(NCH/64, NCHK/4), 256, 0, stream>>>(
        U, DBC, A_log + (size_t)l*EDIM*NST, dt_w + (size_t)l*4*EDIM,
        dt_b + (size_t)l*EDIM, PSP, PSS);
    scanB_k<<<(NCH*16)/256, 256, 0, stream>>>(PSP, PSS);
    scanC_k<<<dim3(NCH/64, NCHK/4), 256, 0, stream>>>(
        U, DBC, A_log + (size_t)l*EDIM*NST, dt_w + (size_t)l*4*EDIM,
        dt_b + (size_t)l*EDIM, PSS, Dp + (size_t)l*EDIM, PROJ, YH, YL);

    // hs += y @ out_w + out_b  [4096 x 1536 -> 768], bf16x3, split-K=2, atomic
    gemm_u<16,3,1><<<dim3(6, 32, 2), 256, 0, stream>>>(
        YH, YL, EDIM, outH, outL, EDIM, out_b + l*HDIM, HS,
        HDIM, EDIM/2, /*zA*/EDIM/2, /*zW*/EDIM/2, 0, 0);

    // bf16 copy of HS for fractal stage1 A-operand
    cvt_k<<<(BLTOK*HDIM)/1024, 256, 0, stream>>>(HS, HSB);

    // fractal: plain bf16 (error attenuated /6), 3 z-batched stages;
    // stage 3 fuses the addscale: HS += silu(.)*(0.5/3) via atomicAdd (zC=0)
    gemm_u<9,1,0><<<dim3(6, 32, 3), 256, 0, stream>>>(
        HSB, nullptr, HDIM, frH, frL, HDIM, frac_b + (size_t)l*3*HDIM, S1,
        HDIM, HDIM, 0, zWf, HDIM, F_HS);
    gemm_u<9,1,0><<<dim3(6, 32, 3), 256, 0, stream>>>(
        S1, nullptr, HDIM, frH, frL, HDIM, frac_b + (size_t)l*3*HDIM, S2,
        HDIM, HDIM, F_HS, zWf, HDIM, F_HS);
    gemm_u<1|16|32,1,0><<<dim3(6, 32, 3), 256, 0, stream>>>(
        S2, nullptr, HDIM, frH, frL, HDIM, frac_b + (size_t)l*3*HDIM, HS,
        HDIM, HDIM, F_HS, zWf, HDIM, 0);
  }

  ln_k<0><<<BLTOK/4, 256, 0, stream>>>(HS, fln_w, fln_b, (float*)d_out, nullptr);
}

// Round 8
// 3509.852 us; speedup vs baseline: 1.1898x; 1.0107x over previous
//
#include <hip/hip_runtime.h>
#include <hip/hip_bf16.h>
#include <stdint.h>

#define NLAYER 8
#define HDIM   768
#define EDIM   1536
#define NST    16
#define LSEQ   2048
#define BATCH  2
#define BLTOK  (BATCH*LSEQ)   /* 4096 tokens */
#define NCH    (BATCH*EDIM)   /* 3072 scan channels */
#define NCHK   64             /* scan time chunks */

typedef unsigned short u16;
typedef short  short8  __attribute__((ext_vector_type(8)));
typedef float  f32x4   __attribute__((ext_vector_type(4)));
typedef unsigned short u16x4 __attribute__((ext_vector_type(4)));

__device__ __forceinline__ float sigm(float x){ return 1.0f/(1.0f+__expf(-x)); }

__device__ __forceinline__ u16 bf16_rne(float x){
  unsigned u = __float_as_uint(x);
  return (u16)((u + 0x7fffu + ((u>>16)&1u)) >> 16);
}
__device__ __forceinline__ float bf16_f(u16 h){
  return __uint_as_float(((unsigned)h)<<16);
}

// async 16B global -> LDS DMA
__device__ __forceinline__ void gload16(const void* g, void* l){
  __builtin_amdgcn_global_load_lds(
    reinterpret_cast<const __attribute__((address_space(1))) unsigned*>(
        reinterpret_cast<uintptr_t>(g)),
    reinterpret_cast<__attribute__((address_space(3))) unsigned*>(
        reinterpret_cast<uintptr_t>(l)),
    16, 0, 0);
}

// ---------------------------------------------------------------------------
// Weight prep (all 4 weight tensors of one layer in ONE launch).
// W[K][Nsrc] fp32 -> H/L[Ndst][K] bf16 hi/lo (transposed).
// Block ranges: [0,2304) in_w | [2304,3456) out_w | [3456,5184) frac x3 |
// [5184,5280) xproj.
// ---------------------------------------------------------------------------
__global__ __launch_bounds__(256) void wprep4_k(
    const float* __restrict__ Win,  u16* __restrict__ inH,  u16* __restrict__ inL,
    const float* __restrict__ Wout, u16* __restrict__ outH, u16* __restrict__ outL,
    const float* __restrict__ Wfr,  u16* __restrict__ frH,  u16* __restrict__ frL,
    const float* __restrict__ Wxp,  u16* __restrict__ xH,   u16* __restrict__ xL)
{
  __shared__ float T[32][33];
  int id = blockIdx.x;
  const float* W; u16 *H; u16 *L; int Nsrc, Ndst, K, bx, by;
  if (id < 2304){
    W=Win; H=inH; L=inL; Nsrc=3072; Ndst=3072; K=768; bx=id%96; by=id/96;
  } else if (id < 3456){
    id-=2304; W=Wout; H=outH; L=outL; Nsrc=768; Ndst=768; K=1536; bx=id%24; by=id/24;
  } else if (id < 5184){
    id-=3456; int z=id/576; id-=z*576;
    W=Wfr+(size_t)z*589824; H=frH+(size_t)z*589824; L=frL+(size_t)z*589824;
    Nsrc=768; Ndst=768; K=768; bx=id%24; by=id/24;
  } else {
    id-=5184; W=Wxp; H=xH; L=xL; Nsrc=36; Ndst=48; K=1536; bx=id%2; by=id/2;
  }
  int n0 = bx*32, k0 = by*32;
  int tx = threadIdx.x&31, ty = threadIdx.x>>5;
  #pragma unroll
  for (int r=0;r<4;r++){
    int kk = ty+8*r, col = n0+tx;
    T[kk][tx] = (col<Nsrc) ? W[(size_t)(k0+kk)*Nsrc+col] : 0.f;
  }
  __syncthreads();
  #pragma unroll
  for (int r=0;r<4;r++){
    int nn = ty+8*r, n = n0+nn, k = k0+tx;
    if (n<Ndst){
      float f = T[tx][nn];
      u16 h = bf16_rne(f);
      H[(size_t)n*K+k] = h;
      L[(size_t)n*K+k] = bf16_rne(f - bf16_f(h));
    }
  }
}

// ---------------------------------------------------------------------------
// Unified MFMA GEMM, DMA-staged, double-buffered, counted-vmcnt pipeline
// + XCD-aware (x,y) block swizzle (T1; all grids have nwg%8==0 -> bijective).
// SPLIT: 3 = bf16x3 (fp32-like), 1 = plain bf16.
// EPI bits: 1=SiLU, 2=C+=v, 8=store bf16 u16, 16=atomicAdd f32,
//           32=scale by 0.5/3 (fractal stage-3 fused addscale).
// ---------------------------------------------------------------------------
template<int EPI, int SPLIT, int SPLITK>
__global__ __launch_bounds__(256) void gemm_u(
    const u16* __restrict__ AH, const u16* __restrict__ AL, int lda,
    const u16* __restrict__ WH, const u16* __restrict__ WL, int ldw,
    const float* __restrict__ bias, void* __restrict__ Cout,
    int N, int Kloop, size_t zA, size_t zW, size_t zB, size_t zC)
{
  constexpr int NPL = (SPLIT==3)?4:2;        // planes per buffer
  constexpr int NLD = (SPLIT==3)?8:4;        // DMA issues/thread/k-step
  __shared__ __align__(16) u16 smem[2*NPL*4096];

  const int z = blockIdx.z;
  const u16* ah = AH + (size_t)z*zA;
  const u16* bh = WH + (size_t)z*zW;
  const u16* al = nullptr;
  const u16* bl = nullptr;
  if constexpr (SPLIT==3){ al = AL + (size_t)z*zA; bl = WL + (size_t)z*zW; }

  // XCD swizzle: chunk the linearized (x,y) grid so each XCD gets a
  // contiguous range -> A-row panels L2-resident per XCD.
  int bx, by;
  {
    const int nx = gridDim.x, nwg = nx*gridDim.y;
    int id = blockIdx.x + nx*blockIdx.y;
    const int q = nwg >> 3;                  // nwg % 8 == 0 for all call sites
    int swz = (id & 7)*q + (id >> 3);
    bx = swz % nx; by = swz / nx;
  }

  const int tid  = threadIdx.x;
  const int m0 = by<<7, n0 = bx<<7;
  const int wave = tid>>6, lane = tid&63;
  const int r = lane&15, q = lane>>4;
  const int wm = (wave&1)<<6, wn = (wave>>1)<<6;
  const int srow = tid>>2;        // 0..63 (row within 64-row half)
  const int scol = (tid&3)*8;     // u16 col offset (0,8,16,24)
  const int sdst = tid*8;         // u16 LDS offset of this thread's 16B

  const int nk = Kloop >> 5;

  auto STAGE = [&](int idx){
    u16* s = smem + (size_t)(idx&1)*NPL*4096;
    const int k0 = idx<<5;
    #pragma unroll
    for (int i=0;i<2;i++){
      const size_t gao = (size_t)(m0 + i*64 + srow)*lda + k0 + scol;
      const size_t gbo = (size_t)(n0 + i*64 + srow)*ldw + k0 + scol;
      const int lo = i*2048 + sdst;
      gload16(ah+gao, s+lo);
      gload16(bh+gbo, s+4096+lo);
      if constexpr (SPLIT==3){
        gload16(al+gao, s+2*4096+lo);
        gload16(bl+gbo, s+3*4096+lo);
      }
    }
  };

  f32x4 acc[4][4];
  #pragma unroll
  for (int i=0;i<4;i++)
    #pragma unroll
    for (int j=0;j<4;j++)
      #pragma unroll
      for (int t=0;t<4;t++) acc[i][j][t]=0.f;

  STAGE(0);
  if (nk > 1) STAGE(1);

  for (int idx = 0; idx < nk; idx++){
    // wait for buf[idx&1]'s loads only; keep next tile's NLD in flight
    if (idx+1 < nk) asm volatile("s_waitcnt vmcnt(%0)" :: "n"(NLD) : "memory");
    else            asm volatile("s_waitcnt vmcnt(0)" ::: "memory");
    __builtin_amdgcn_s_barrier();

    const u16* s = smem + (size_t)(idx&1)*NPL*4096;
    const u16* sA = s;
    const u16* sB = s + 4096;

    short8 aHf[4], bHf[4];
    #pragma unroll
    for (int i=0;i<4;i++) aHf[i] = *(const short8*)&sA[(wm + 16*i + r)*32 + q*8];
    #pragma unroll
    for (int j=0;j<4;j++) bHf[j] = *(const short8*)&sB[(wn + 16*j + r)*32 + q*8];
    short8 aLf[4], bLf[4];
    if constexpr (SPLIT==3){
      const u16* sAL = s + 2*4096;
      const u16* sBL = s + 3*4096;
      #pragma unroll
      for (int i=0;i<4;i++) aLf[i] = *(const short8*)&sAL[(wm + 16*i + r)*32 + q*8];
      #pragma unroll
      for (int j=0;j<4;j++) bLf[j] = *(const short8*)&sBL[(wn + 16*j + r)*32 + q*8];
    }
    // frags drained to regs before allowing overwrite of this buffer
    asm volatile("s_waitcnt lgkmcnt(0)" ::: "memory");
    __builtin_amdgcn_sched_barrier(0);
    __builtin_amdgcn_s_barrier();

    if (idx+2 < nk) STAGE(idx+2);   // overlaps MFMA below

    if constexpr (SPLIT==3){
      #pragma unroll
      for (int i=0;i<4;i++)
        #pragma unroll
        for (int j=0;j<4;j++){
          acc[i][j] = __builtin_amdgcn_mfma_f32_16x16x32_bf16(aHf[i], bHf[j], acc[i][j], 0,0,0);
          acc[i][j] = __builtin_amdgcn_mfma_f32_16x16x32_bf16(aHf[i], bLf[j], acc[i][j], 0,0,0);
          acc[i][j] = __builtin_amdgcn_mfma_f32_16x16x32_bf16(aLf[i], bHf[j], acc[i][j], 0,0,0);
        }
    } else {
      #pragma unroll
      for (int i=0;i<4;i++)
        #pragma unroll
        for (int j=0;j<4;j++)
          acc[i][j] = __builtin_amdgcn_mfma_f32_16x16x32_bf16(aHf[i], bHf[j], acc[i][j], 0,0,0);
    }
  }

  float* Cf = (float*)Cout + (size_t)z*zC;
  u16*   Cu = (u16*)Cout   + (size_t)z*zC;
  const float* bz = bias ? (bias + (size_t)z*zB) : bias;
  #pragma unroll
  for (int j=0;j<4;j++){
    int n_out = n0 + wn + 16*j + r;
    float bv = (bz && (!SPLITK || z==0)) ? bz[n_out] : 0.f;
    #pragma unroll
    for (int i=0;i<4;i++){
      #pragma unroll
      for (int reg=0;reg<4;reg++){
        int m_out = m0 + wm + 16*i + 4*q + reg;
        float v = acc[i][j][reg] + bv;
        if (EPI & 1)  v *= sigm(v);
        if (EPI & 32) v *= (0.5f/3.0f);
        size_t o = (size_t)m_out*N + n_out;
        if      (EPI & 16) atomicAdd(&Cf[o], v);
        else if (EPI & 8)  Cu[o] = bf16_rne(v);
        else if (EPI & 2)  Cf[o] += v;
        else               Cf[o] = v;
      }
    }
  }
}

// ---------------------------------------------------------------------------
// xproj GEMM: DBC[4096][36] = U[4096][1536] @ xw; pre-split xwT[48][1536].
// Split-K x4: 256 threads, wave w covers K in [w*384,(w+1)*384); LDS reduce.
// ---------------------------------------------------------------------------
__global__ __launch_bounds__(256) void xgemm_k(
    const float* __restrict__ A, const u16* __restrict__ XH,
    const u16* __restrict__ XL, float* __restrict__ DBC)
{
  __shared__ f32x4 red[3][4][64];   // 12 KB
  int m0 = blockIdx.x*16;
  int wv = threadIdx.x>>6, lane = threadIdx.x&63;
  int r = lane&15, q = lane>>4;
  f32x4 acc[3];
  #pragma unroll
  for (int j=0;j<3;j++)
    #pragma unroll
    for (int t=0;t<4;t++) acc[j][t]=0.f;

  const int KW = EDIM/4;           // 384
  const int kend = (wv+1)*KW;
  for (int k0 = wv*KW; k0 < kend; k0 += 32){
    const float* ap = A + (size_t)(m0+r)*EDIM + k0 + q*8;
    float f[8];
    *(float4*)&f[0] = *(const float4*)(ap+0);
    *(float4*)&f[4] = *(const float4*)(ap+4);
    short8 ah, al;
    #pragma unroll
    for (int t=0;t<8;t++){
      u16 h = bf16_rne(f[t]);
      ah[t] = (short)h;
      al[t] = (short)bf16_rne(f[t]-bf16_f(h));
    }
    #pragma unroll
    for (int j=0;j<3;j++){
      size_t o = (size_t)(16*j+r)*EDIM + k0 + q*8;
      short8 bh = *(const short8*)&XH[o];
      short8 bl = *(const short8*)&XL[o];
      acc[j] = __builtin_amdgcn_mfma_f32_16x16x32_bf16(ah, bh, acc[j], 0,0,0);
      acc[j] = __builtin_amdgcn_mfma_f32_16x16x32_bf16(ah, bl, acc[j], 0,0,0);
      acc[j] = __builtin_amdgcn_mfma_f32_16x16x32_bf16(al, bh, acc[j], 0,0,0);
    }
  }
  #pragma unroll
  for (int j=0;j<3;j++) red[j][wv][lane] = acc[j];
  __syncthreads();
  if (wv == 0){
    #pragma unroll
    for (int j=0;j<3;j++){
      f32x4 s = red[j][0][lane];
      s += red[j][1][lane];
      s += red[j][2][lane];
      s += red[j][3][lane];
      int n = 16*j + r;
      if (n < 36){
        #pragma unroll
        for (int reg=0;reg<4;reg++){
          int m = m0 + 4*q + reg;
          DBC[(size_t)m*36 + n] = s[reg];
        }
      }
    }
  }
}

// ---------------------------------------------------------------------------
__global__ __launch_bounds__(256) void embed_k(
    const int* __restrict__ ids, const float* __restrict__ tok,
    const float* __restrict__ pos, float* __restrict__ HS)
{
  int idx = blockIdx.x*256 + threadIdx.x;
  int h = idx % HDIM; int t = idx / HDIM;
  int lpos = t % LSEQ;
  int id = ids[t];
  HS[idx] = tok[id*HDIM + h] + pos[lpos*HDIM + h];
}

// ---------------------------------------------------------------------------
// Wave-per-token LN (no barriers, no LDS). 4 tokens/block.
// PACK=1: write bf16 hi/lo planes (O1=H, O2=L). PACK=0: fp32 to O1.
template<int PACK>
__global__ __launch_bounds__(256) void ln_k(
    const float* __restrict__ X, const float* __restrict__ w,
    const float* __restrict__ b, void* __restrict__ O1, void* __restrict__ O2)
{
  int wv = threadIdx.x>>6, lane = threadIdx.x&63;
  int t = blockIdx.x*4 + wv;
  const float* x = X + (size_t)t*HDIM;
  float v[12];
  float s=0.f, s2=0.f;
  #pragma unroll
  for (int k=0;k<12;k++){
    v[k] = x[lane + 64*k];
    s += v[k]; s2 += v[k]*v[k];
  }
  #pragma unroll
  for (int off=32; off; off>>=1){
    s  += __shfl_xor(s,  off, 64);
    s2 += __shfl_xor(s2, off, 64);
  }
  float m = s/HDIM, rr = rsqrtf(s2/HDIM - m*m + 1e-5f);
  #pragma unroll
  for (int k=0;k<12;k++){
    int i = lane + 64*k;
    float o = (v[k]-m)*rr*w[i] + b[i];
    if (PACK){
      u16 h = bf16_rne(o);
      ((u16*)O1)[(size_t)t*HDIM+i] = h;
      ((u16*)O2)[(size_t)t*HDIM+i] = bf16_rne(o - bf16_f(h));
    } else {
      ((float*)O1)[(size_t)t*HDIM+i] = o;
    }
  }
}

// fp32 -> bf16 (hi only) convert, 4 elems/thread
__global__ __launch_bounds__(256) void cvt_k(
    const float* __restrict__ X, u16* __restrict__ O)
{
  int i = blockIdx.x*256 + threadIdx.x;
  float4 v = ((const float4*)X)[i];
  u16x4 o;
  o[0]=bf16_rne(v.x); o[1]=bf16_rne(v.y); o[2]=bf16_rne(v.z); o[3]=bf16_rne(v.w);
  ((u16x4*)O)[i] = o;
}

// ---------------------------------------------------------------------------
__global__ __launch_bounds__(256) void conv_silu_k(
    const float* __restrict__ PROJ, const float* __restrict__ cw,
    const float* __restrict__ cb, float* __restrict__ U)
{
  int idx = blockIdx.x*256 + threadIdx.x;
  int e = idx % EDIM; int t = idx / EDIM;
  int l = t % LSEQ; int tb = t - l;
  float acc = cb[e];
  #pragma unroll
  for (int j=0;j<4;j++){
    int tt = l + j - 3;
    if (tt >= 0) acc += PROJ[(size_t)(tb+tt)*(2*EDIM) + e] * cw[e*4+j];
  }
  U[idx] = acc * sigm(acc);
}

// ---------------------------------------------------------------------------
// Coalesced chunked scan: thread = (channel, chunk), 16 states in registers.
// ---------------------------------------------------------------------------
__global__ __launch_bounds__(256) void scanA_k(
    const float* __restrict__ U, const float* __restrict__ DBC,
    const float* __restrict__ Alog, const float* __restrict__ dtw,
    const float* __restrict__ dtb, float* __restrict__ PSP,
    float* __restrict__ PSS)
{
  const int CH = LSEQ/NCHK;
  int el = threadIdx.x & 63, jj = threadIdx.x >> 6;
  int ch = blockIdx.x*64 + el;
  int j  = blockIdx.y*4 + jj;
  int e = ch % EDIM, b = ch / EDIM;

  float a[16], P[16], S[16];
  #pragma unroll
  for (int n=0;n<16;n++){ a[n] = -__expf(Alog[e*NST+n]); P[n]=1.f; S[n]=0.f; }
  float w0=dtw[e], w1=dtw[EDIM+e], w2=dtw[2*EDIM+e], w3=dtw[3*EDIM+e];
  float db=dtb[e];
  size_t base=(size_t)b*LSEQ;

  for (int t=j*CH; t<j*CH+CH; t++){
    size_t tok = base+t;
    float4 d4 = *(const float4*)&DBC[tok*36];
    float4 B0 = *(const float4*)&DBC[tok*36+4];
    float4 B1 = *(const float4*)&DBC[tok*36+8];
    float4 B2 = *(const float4*)&DBC[tok*36+12];
    float4 B3 = *(const float4*)&DBC[tok*36+16];
    float dt = d4.x*w0 + d4.y*w1 + d4.z*w2 + d4.w*w3 + db;
    dt = (dt>20.f)?dt:log1pf(__expf(dt));
    float du = dt * U[tok*EDIM+e];
    float Bv[16];
    *(float4*)&Bv[0]=B0; *(float4*)&Bv[4]=B1; *(float4*)&Bv[8]=B2; *(float4*)&Bv[12]=B3;
    #pragma unroll
    for (int n=0;n<16;n++){
      float dA = __expf(dt*a[n]);
      P[n]*=dA; S[n]=S[n]*dA + du*Bv[n];
    }
  }
  #pragma unroll
  for (int n=0;n<16;n++){
    PSP[(size_t)(j*16+n)*NCH + ch] = P[n];
    PSS[(size_t)(j*16+n)*NCH + ch] = S[n];
  }
}

// Sequential combine over chunks; rewrites PSS in place with the INCOMING
// state of each chunk (consumed by scanC).
__global__ __launch_bounds__(256) void scanB_k(
    const float* __restrict__ PSP, float* __restrict__ PSS)
{
  int idx = blockIdx.x*256 + threadIdx.x;   // over NCH*16
  int n = idx / NCH, ch = idx % NCH;
  float hin = 0.f;
  #pragma unroll 4
  for (int jj=0;jj<NCHK;jj++){
    size_t o = (size_t)(jj*16+n)*NCH + ch;
    float p = PSP[o], s = PSS[o];
    PSS[o] = hin;
    hin = p*hin + s;
  }
}

__global__ __launch_bounds__(256) void scanC_k(
    const float* __restrict__ U, const float* __restrict__ DBC,
    const float* __restrict__ Alog, const float* __restrict__ dtw,
    const float* __restrict__ dtb, const float* __restrict__ HIN,
    const float* __restrict__ Dp, const float* __restrict__ PROJ,
    u16* __restrict__ YH, u16* __restrict__ YL)
{
  const int CH = LSEQ/NCHK;
  int el = threadIdx.x & 63, jj = threadIdx.x >> 6;
  int ch = blockIdx.x*64 + el;
  int j  = blockIdx.y*4 + jj;
  int e = ch % EDIM, b = ch / EDIM;

  float a[16], h[16];
  #pragma unroll
  for (int n=0;n<16;n++){
    a[n] = -__expf(Alog[e*NST+n]);
    h[n] = HIN[(size_t)(j*16+n)*NCH + ch];
  }
  float w0=dtw[e], w1=dtw[EDIM+e], w2=dtw[2*EDIM+e], w3=dtw[3*EDIM+e];
  float db=dtb[e], dcf=Dp[e];
  size_t base=(size_t)b*LSEQ;

  for (int t=j*CH; t<j*CH+CH; t++){
    size_t tok = base+t;
    float4 d4 = *(const float4*)&DBC[tok*36];
    float4 B0 = *(const float4*)&DBC[tok*36+4];
    float4 B1 = *(const float4*)&DBC[tok*36+8];
    float4 B2 = *(const float4*)&DBC[tok*36+12];
    float4 B3 = *(const float4*)&DBC[tok*36+16];
    float4 C0 = *(const float4*)&DBC[tok*36+20];
    float4 C1 = *(const float4*)&DBC[tok*36+24];
    float4 C2 = *(const float4*)&DBC[tok*36+28];
    float4 C3 = *(const float4*)&DBC[tok*36+32];
    float dt = d4.x*w0 + d4.y*w1 + d4.z*w2 + d4.w*w3 + db;
    dt = (dt>20.f)?dt:log1pf(__expf(dt));
    float u = U[tok*EDIM+e];
    float du = dt * u;
    float Bv[16], Cv[16];
    *(float4*)&Bv[0]=B0; *(float4*)&Bv[4]=B1; *(float4*)&Bv[8]=B2; *(float4*)&Bv[12]=B3;
    *(float4*)&Cv[0]=C0; *(float4*)&Cv[4]=C1; *(float4*)&Cv[8]=C2; *(float4*)&Cv[12]=C3;
    float y = 0.f;
    #pragma unroll
    for (int n=0;n<16;n++){
      float dA = __expf(dt*a[n]);
      h[n] = h[n]*dA + du*Bv[n];
      y += h[n]*Cv[n];
    }
    float g = PROJ[tok*(2*EDIM) + EDIM + e];
    float yv = (y + u*dcf)*sigm(g);
    u16 hh = bf16_rne(yv);
    YH[tok*EDIM + e] = hh;
    YL[tok*EDIM + e] = bf16_rne(yv - bf16_f(hh));
  }
}

// ---------------------------------------------------------------------------
extern "C" void kernel_launch(void* const* d_in, const int* in_sizes, int n_in,
                              void* d_out, int out_size, void* d_ws, size_t ws_size,
                              hipStream_t stream)
{
  const int*   ids      = (const int*)d_in[0];
  const float* tok_emb  = (const float*)d_in[1];
  const float* pos_emb  = (const float*)d_in[2];
  const float* ln_w     = (const float*)d_in[3];
  const float* ln_b     = (const float*)d_in[4];
  const float* in_w     = (const float*)d_in[5];
  const float* in_b     = (const float*)d_in[6];
  const float* conv_w   = (const float*)d_in[7];
  const float* conv_b   = (const float*)d_in[8];
  const float* xproj_w  = (const float*)d_in[9];
  const float* dt_w     = (const float*)d_in[10];
  const float* dt_b     = (const float*)d_in[11];
  const float* A_log    = (const float*)d_in[12];
  const float* Dp       = (const float*)d_in[13];
  const float* out_w    = (const float*)d_in[14];
  const float* out_b    = (const float*)d_in[15];
  const float* frac_w   = (const float*)d_in[16];
  const float* frac_b   = (const float*)d_in[17];
  const float* fln_w    = (const float*)d_in[18];
  const float* fln_b    = (const float*)d_in[19];

  // ---- workspace map
  const size_t F_HS   = (size_t)BLTOK*HDIM;      // 3,145,728 floats
  const size_t F_PROJ = (size_t)BLTOK*2*EDIM;    // 12,582,912
  const size_t F_R1   = (size_t)BLTOK*EDIM;      //  6,291,456
  float* HS   = (float*)d_ws;
  float* PROJ = HS   + F_HS;
  float* R1   = PROJ + F_PROJ;                   // XH/XL, then U
  float* DBC  = R1   + F_R1;
  u16* W16  = (u16*)(DBC + (size_t)BLTOK*36);
  u16* inH  = W16;
  u16* inL  = inH  + (size_t)2359296;
  u16* outH = inL  + (size_t)2359296;
  u16* outL = outH + (size_t)1179648;
  u16* frH  = outL + (size_t)1179648;
  u16* frL  = frH  + (size_t)1769472;
  u16* xH   = frL  + (size_t)1769472;
  u16* xL   = xH   + (size_t)73728;
  float* PSP = (float*)(xL + (size_t)73728);
  float* PSS = PSP + (size_t)NCHK*16*NCH;        // 12.6 MB each
  u16* YH  = (u16*)(PSS + (size_t)NCHK*16*NCH);  // 4096x1536 u16
  u16* YL  = YH + (size_t)BLTOK*EDIM;
  // aliases
  u16*   XH  = (u16*)R1;                         // LN hi plane (dead before U)
  u16*   XL  = XH + F_HS;                        // LN lo plane
  float* U   = R1;                               // fp32 conv out (overwrites X)
  u16*   HSB = (u16*)PSP;                        // bf16(HS), PSP dead post-scanB
  u16*   S1  = (u16*)(PROJ + 3*F_HS);            // stage1 out, 3*F_HS u16
  u16*   S2  = S1 + 3*F_HS;                      // stage2 out, 3*F_HS u16

  embed_k<<<(BLTOK*HDIM)/256, 256, 0, stream>>>(ids, tok_emb, pos_emb, HS);

  const size_t zWf = (size_t)HDIM*HDIM;
  for (int l = 0; l < NLAYER; l++){
    // all 4 weight preps in one launch
    wprep4_k<<<5280, 256, 0, stream>>>(
        in_w   + (size_t)l*HDIM*2*EDIM, inH, inL,
        out_w  + (size_t)l*EDIM*HDIM,  outH, outL,
        frac_w + (size_t)l*3*HDIM*HDIM, frH, frL,
        xproj_w+ (size_t)l*EDIM*36,    xH,  xL);

    // LN -> bf16 hi/lo planes (wave-per-token)
    ln_k<1><<<BLTOK/4, 256, 0, stream>>>(HS, ln_w + l*HDIM, ln_b + l*HDIM, XH, XL);

    // proj = LN(hs) @ in_w + in_b   [4096 x 768 -> 3072], bf16x3
    gemm_u<0,3,0><<<dim3(24, 32), 256, 0, stream>>>(
        XH, XL, HDIM, inH, inL, HDIM, in_b + l*2*EDIM, PROJ,
        2*EDIM, HDIM, 0,0,0,0);

    conv_silu_k<<<(BLTOK*EDIM)/256, 256, 0, stream>>>(
        PROJ, conv_w + l*EDIM*4, conv_b + l*EDIM, U);

    // dbc = u @ xproj_w (split-K x4)
    xgemm_k<<<BLTOK/16, 256, 0, stream>>>(U, xH, xL, DBC);

    // selective scan (coalesced 3-phase), Y -> bf16 hi/lo planes
    scanA_k<<<dim3(NCH/64, NCHK/4), 256, 0, stream>>>(
        U, DBC, A_log + (size_t)l*EDIM*NST, dt_w + (size_t)l*4*EDIM,
        dt_b + (size_t)l*EDIM, PSP, PSS);
    scanB_k<<<(NCH*16)/256, 256, 0, stream>>>(PSP, PSS);
    scanC_k<<<dim3(NCH/64, NCHK/4), 256, 0, stream>>>(
        U, DBC, A_log + (size_t)l*EDIM*NST, dt_w + (size_t)l*4*EDIM,
        dt_b + (size_t)l*EDIM, PSS, Dp + (size_t)l*EDIM, PROJ, YH, YL);

    // hs += y @ out_w + out_b  [4096 x 1536 -> 768], bf16x3, split-K=4, atomic
    gemm_u<16,3,1><<<dim3(6, 32, 4), 256, 0, stream>>>(
        YH, YL, EDIM, outH, outL, EDIM, out_b + l*HDIM, HS,
        HDIM, EDIM/4, /*zA*/EDIM/4, /*zW*/EDIM/4, 0, 0);

    // bf16 copy of HS for fractal stage1 A-operand
    cvt_k<<<(BLTOK*HDIM)/1024, 256, 0, stream>>>(HS, HSB);

    // fractal: plain bf16 (error attenuated /6), 3 z-batched stages;
    // stage 3 fuses the addscale: HS += silu(.)*(0.5/3) via atomicAdd (zC=0)
    gemm_u<9,1,0><<<dim3(6, 32, 3), 256, 0, stream>>>(
        HSB, nullptr, HDIM, frH, frL, HDIM, frac_b + (size_t)l*3*HDIM, S1,
        HDIM, HDIM, 0, zWf, HDIM, F_HS);
    gemm_u<9,1,0><<<dim3(6, 32, 3), 256, 0, stream>>>(
        S1, nullptr, HDIM, frH, frL, HDIM, frac_b + (size_t)l*3*HDIM, S2,
        HDIM, HDIM, F_HS, zWf, HDIM, F_HS);
    gemm_u<1|16|32,1,0><<<dim3(6, 32, 3), 256, 0, stream>>>(
        S2, nullptr, HDIM, frH, frL, HDIM, frac_b + (size_t)l*3*HDIM, HS,
        HDIM, HDIM, F_HS, zWf, HDIM, 0);
  }

  ln_k<0><<<BLTOK/4, 256, 0, stream>>>(HS, fln_w, fln_b, (float*)d_out, nullptr);
}